// Round 6
// baseline (1111.781 us; speedup 1.0000x reference)
//
#include <hip/hip_runtime.h>
#include <cmath>

typedef unsigned short u16;
typedef unsigned short u16x2 __attribute__((ext_vector_type(2)));
typedef unsigned short u16x4 __attribute__((ext_vector_type(4)));
typedef unsigned short u16x8 __attribute__((ext_vector_type(8)));
typedef short s16x8 __attribute__((ext_vector_type(8)));
typedef float f32x4 __attribute__((ext_vector_type(4)));
typedef float f32x2 __attribute__((ext_vector_type(2)));

#define B_SZ 16
#define HW 56
#define L_TOK 3136      // 56*56
#define C_DIM 512
#define NHEAD 16
#define DHEAD 32
#define WS7 7
#define NWIN 49
#define ROWS_TOTAL 50176   // 16*3136
#define MLP_DIM 2048

__device__ __forceinline__ float bf2f(u16 u) {
    union { unsigned int i; float f; } z;
    z.i = ((unsigned int)u) << 16;
    return z.f;
}
__device__ __forceinline__ u16 f2bf(float f) {
    union { float f; unsigned int i; } z;
    z.f = f;
    unsigned int r = z.i + 0x7fffu + ((z.i >> 16) & 1u);
    return (u16)(r >> 16);
}

// async global->LDS, 16B per lane; LDS dest = wave-uniform base + lane*16
__device__ __forceinline__ void gl_lds16(const u16* g, u16* l) {
    __builtin_amdgcn_global_load_lds(
        (const __attribute__((address_space(1))) unsigned int*)g,
        (__attribute__((address_space(3))) unsigned int*)l,
        16, 0, 0);
}

// ---------------------------------------------------------------------------
// 1) mod = silu(emb) @ adaLN_w + adaLN_b -> fp32 [16,3072]
// ---------------------------------------------------------------------------
__global__ __launch_bounds__(256)
void mod_kernel(const float* __restrict__ emb, const float* __restrict__ w,
                const float* __restrict__ bias, float* __restrict__ mod)
{
    int b = blockIdx.y;
    int o = blockIdx.x * 256 + threadIdx.x;
    __shared__ float se[512];
    for (int i = threadIdx.x; i < 512; i += 256) {
        float e = emb[b * 512 + i];
        se[i] = e / (1.0f + expf(-e));
    }
    __syncthreads();
    float acc = bias[o];
    #pragma unroll 8
    for (int k = 0; k < 512; ++k)
        acc += se[k] * w[(size_t)k * 3072 + o];
    mod[b * 3072 + o] = acc;
}

// ---------------------------------------------------------------------------
// 2) weight transpose + bf16 cast: Wt[n][k] = bf16(W[k][n])
// ---------------------------------------------------------------------------
__global__ __launch_bounds__(1024)
void transpose_kernel(const float* __restrict__ W, u16* __restrict__ Wt, int K, int N)
{
    __shared__ float tile[32][33];
    int k0 = blockIdx.x * 32, n0 = blockIdx.y * 32;
    tile[threadIdx.y][threadIdx.x] = W[(size_t)(k0 + threadIdx.y) * N + (n0 + threadIdx.x)];
    __syncthreads();
    Wt[(size_t)(n0 + threadIdx.y) * K + (k0 + threadIdx.x)] = f2bf(tile[threadIdx.x][threadIdx.y]);
}

// ---------------------------------------------------------------------------
// 3) LN + adaLN modulate; wave-per-row (4 rows/block), no LDS / syncthreads.
// ---------------------------------------------------------------------------
template<int WINDOWED>
__global__ __launch_bounds__(256)
void ln_kernel(const float* __restrict__ xin, const float* __restrict__ mod,
               u16* __restrict__ out, int shOff, int scOff, int rowBase)
{
    int wv   = threadIdx.x >> 6;
    int lane = threadIdx.x & 63;
    int rbl = blockIdx.x * 4 + wv;        // chunk-local row
    int rb  = rbl + rowBase;              // global sequence row
    int b = rb / L_TOK, l = rb - b * L_TOK;
    const float* xr = xin + (size_t)rb * C_DIM;
    int c0 = lane * 8;
    f32x4 u0 = *(const f32x4*)(xr + c0);
    f32x4 u1 = *(const f32x4*)(xr + c0 + 4);
    float s = u0.x + u0.y + u0.z + u0.w + u1.x + u1.y + u1.z + u1.w;
    float q = u0.x*u0.x + u0.y*u0.y + u0.z*u0.z + u0.w*u0.w
            + u1.x*u1.x + u1.y*u1.y + u1.z*u1.z + u1.w*u1.w;
    #pragma unroll
    for (int off = 32; off > 0; off >>= 1) {
        s += __shfl_xor(s, off);
        q += __shfl_xor(q, off);
    }
    float mu = s * (1.0f / 512.0f);
    float var = q * (1.0f / 512.0f) - mu * mu;
    float rstd = rsqrtf(var + 1e-6f);
    const float* mb = mod + b * 3072;
    f32x4 sc0 = *(const f32x4*)(mb + scOff + c0);
    f32x4 sc1 = *(const f32x4*)(mb + scOff + c0 + 4);
    f32x4 sh0 = *(const f32x4*)(mb + shOff + c0);
    f32x4 sh1 = *(const f32x4*)(mb + shOff + c0 + 4);
    float y[8];
    y[0] = (u0.x - mu) * rstd * (1.0f + sc0.x) + sh0.x;
    y[1] = (u0.y - mu) * rstd * (1.0f + sc0.y) + sh0.y;
    y[2] = (u0.z - mu) * rstd * (1.0f + sc0.z) + sh0.z;
    y[3] = (u0.w - mu) * rstd * (1.0f + sc0.w) + sh0.w;
    y[4] = (u1.x - mu) * rstd * (1.0f + sc1.x) + sh1.x;
    y[5] = (u1.y - mu) * rstd * (1.0f + sc1.y) + sh1.y;
    y[6] = (u1.z - mu) * rstd * (1.0f + sc1.z) + sh1.z;
    y[7] = (u1.w - mu) * rstd * (1.0f + sc1.w) + sh1.w;
    size_t drow;
    if (WINDOWED) {
        int hh = l / HW, ww = l - hh * HW;
        int hs = hh - 3; if (hs < 0) hs += HW;
        int ws2 = ww - 3; if (ws2 < 0) ws2 += HW;
        int wi = (hs / WS7) * 8 + (ws2 / WS7);
        int n  = (hs % WS7) * WS7 + (ws2 % WS7);
        int b_local = rbl / L_TOK;
        drow = (size_t)((b_local * 64 + wi) * NWIN + n);
    } else {
        drow = (size_t)rbl;
    }
    u16x8 o;
    #pragma unroll
    for (int i = 0; i < 8; ++i) o[i] = f2bf(y[i]);
    *(u16x8*)(out + drow * C_DIM + c0) = o;
}

// ---------------------------------------------------------------------------
// 4) GEMM: C[M,N] = A[M,K] @ Bt[N,K]^T + bias
//    128x128 tile, BK=32, 4 waves x (4x4) mfma_f32_16x16x32_bf16.
//    Depth-3 pipeline: 4 static LDS buffers (64 KB), counted vmcnt(8).
//    Buffer mapping: tile T lives in buffer T%4.  The phase computing
//    tile t (buffer t%4) stages tile t+3 into buffer (t+3)%4 — the buffer
//    freed by last phase's compute.  (Round-5 bug: staged into the buffer
//    being computed -> async writes raced the ds_reads -> NaN.)
//    Invariant: 12 own gl_lds outstanding at each phase top (tiles t..t+2);
//    vmcnt(8) retires exactly tile t.  One barrier per K-step; lgkmcnt(0)
//    folded into the wait; sched_barrier(0) pins epilogue/loop boundaries.
//    Requires nt = K/32 multiple of 4, >= 8 (K=512/2048 qualify).
//    LDS chunk swizzle (both-sides, rule #21): logical chunk q of row r
//    stored at physical chunk q^((r>>1)&3); write side via pre-swizzled
//    per-lane GLOBAL column, read side via lane-constant XOR on quad.
//    8-way ds_read bank conflict -> 2-way (free).
// ---------------------------------------------------------------------------
template<int EPI>
__global__ __launch_bounds__(256)
void gemm128(const u16* __restrict__ A, const u16* __restrict__ Bt,
             const float* __restrict__ bias, void* __restrict__ outv,
             const float* __restrict__ resid, const float* __restrict__ mod,
             int N, int K, int rowOffset, int nyb)
{
    __shared__ u16 sA[4][128][32];   // 32 KB
    __shared__ u16 sB[4][128][32];   // 32 KB
    const int tid  = threadIdx.x;
    const int lane = tid & 63;
    const int wave = tid >> 6;
    const int wr = (wave >> 1) * 64;
    const int wc = (wave & 1) * 64;
    const int quad = lane >> 4;
    const int mrow = lane & 15;

    // bijective XCD-chunked swizzle (m204), col-block fastest within chunk
    const int nwg  = gridDim.x;
    const int orig = blockIdx.x;
    const int xq = nwg >> 3, xr = nwg & 7;
    const int xcd = orig & 7, xidx = orig >> 3;
    const int wgid = (xcd < xr ? xcd * (xq + 1)
                               : xr * (xq + 1) + (xcd - xr) * xq) + xidx;
    const int bx = wgid / nyb;
    const int by = wgid - bx * nyb;
    const int rowBase = bx * 128;
    const int colBase = by * 128;

    const int r0   = wave * 32;
    const int lrow = lane >> 2;
    // pre-swizzled global source chunk: lane writes physical chunk (lane&3)
    // of LDS row r0+(lane>>2); that slot holds logical chunk (lane&3)^((lane>>3)&3)
    const int lcol = ((lane & 3) ^ ((lane >> 3) & 3)) * 8;
    const u16* gA = A  + (size_t)(rowBase + r0 + lrow) * K + lcol;
    const u16* gB = Bt + (size_t)(colBase + r0 + lrow) * K + lcol;
    const size_t gstep = (size_t)16 * K;
    // read-side physical chunk for logical k-chunk 'quad' of row wr+tt*16+mrow
    const int cq = (quad ^ ((mrow >> 1) & 3)) * 8;

    f32x4 acc[4][4] = {};
    const int nt = K >> 5;   // multiple of 4, >= 8

#define STAGE(bi, kk) do {                                 \
    gl_lds16(gA + (kk),         &sA[bi][r0][0]);           \
    gl_lds16(gA + (kk) + gstep, &sA[bi][r0 + 16][0]);      \
    gl_lds16(gB + (kk),         &sB[bi][r0][0]);           \
    gl_lds16(gB + (kk) + gstep, &sB[bi][r0 + 16][0]);      \
} while (0)

#define COMPUTE(bi)                                                        \
    {                                                                      \
        s16x8 af[4], bg[4];                                                \
        _Pragma("unroll")                                                  \
        for (int tt = 0; tt < 4; ++tt) {                                   \
            af[tt] = *(const s16x8*)&sA[bi][wr + tt * 16 + mrow][cq];      \
            bg[tt] = *(const s16x8*)&sB[bi][wc + tt * 16 + mrow][cq];      \
        }                                                                  \
        _Pragma("unroll")                                                  \
        for (int tm = 0; tm < 4; ++tm)                                     \
            _Pragma("unroll")                                              \
            for (int tn = 0; tn < 4; ++tn)                                 \
                acc[tm][tn] = __builtin_amdgcn_mfma_f32_16x16x32_bf16(     \
                    af[tm], bg[tn], acc[tm][tn], 0, 0, 0);                 \
    }

#define WAIT8() asm volatile("s_waitcnt vmcnt(8) lgkmcnt(0)" ::: "memory")
#define WAIT4() asm volatile("s_waitcnt vmcnt(4) lgkmcnt(0)" ::: "memory")
#define WAIT0() asm volatile("s_waitcnt vmcnt(0) lgkmcnt(0)" ::: "memory")
#define BAR()   do { __builtin_amdgcn_s_barrier();                         \
                     __builtin_amdgcn_sched_barrier(0); } while (0)

    STAGE(0, 0);
    STAGE(1, 32);
    STAGE(2, 64);
    // invariant at each phase top: tiles t, t+1, t+2 in flight (12 loads)

    for (int t = 0; t < nt - 4; t += 4) {
        // compute tile t   (buf 0); stage tile t+3 -> buf 3 (freed last phase)
        WAIT8(); BAR(); STAGE(3, (t + 3) << 5); COMPUTE(0);
        WAIT8(); BAR(); STAGE(0, (t + 4) << 5); COMPUTE(1);
        WAIT8(); BAR(); STAGE(1, (t + 5) << 5); COMPUTE(2);
        WAIT8(); BAR(); STAGE(2, (t + 6) << 5); COMPUTE(3);
    }
    // t = nt-4: stage final tile nt-1 into buffer 3
    WAIT8(); BAR(); STAGE(3, (nt - 1) << 5); COMPUTE(0);
    // t = nt-3: 12 outstanding -> oldest 4 = tile nt-3
    WAIT8(); BAR(); COMPUTE(1);
    // t = nt-2: 8 outstanding
    WAIT4(); BAR(); COMPUTE(2);
    // t = nt-1: drain
    WAIT0(); BAR(); COMPUTE(3);

#undef STAGE
#undef COMPUTE
#undef WAIT8
#undef WAIT4
#undef WAIT0
#undef BAR

    #pragma unroll
    for (int tm = 0; tm < 4; ++tm) {
        #pragma unroll
        for (int tn = 0; tn < 4; ++tn) {
            int col = colBase + wc + tn * 16 + mrow;
            float bv = bias[col];
            #pragma unroll
            for (int i = 0; i < 4; ++i) {
                int r = rowBase + wr + tm * 16 + quad * 4 + i;   // chunk-local
                float v = acc[tm][tn][i] + bv;
                if constexpr (EPI == 0) {
                    ((u16*)outv)[(size_t)r * N + col] = f2bf(v);
                } else if constexpr (EPI == 1) {
                    float g = 0.5f * v * (1.0f + erff(v * 0.70710678118654752f));
                    ((u16*)outv)[(size_t)r * N + col] = f2bf(g);
                } else if constexpr (EPI == 2) {
                    int rg = r + rowOffset;        // global window-layout row
                    int b = rg / L_TOK;
                    int rem = rg - b * L_TOK;
                    int wi = rem / NWIN;
                    int n  = rem - wi * NWIN;
                    int hs  = (wi >> 3) * WS7 + n / WS7;
                    int ws2 = (wi & 7) * WS7 + n % WS7;
                    int hh = hs + 3;  if (hh >= HW)  hh -= HW;
                    int ww = ws2 + 3; if (ww >= HW)  ww -= HW;
                    size_t dst = ((size_t)(b * L_TOK + hh * HW + ww)) * C_DIM + col;
                    float g = mod[b * 3072 + 1024 + col];
                    ((float*)outv)[dst] = resid[dst] + g * v;
                } else {  // EPI == 3
                    int rg = r + rowOffset;        // global sequence row
                    int b = rg / L_TOK;
                    size_t dst = (size_t)rg * C_DIM + col;
                    float g = mod[b * 3072 + 2560 + col];
                    ((float*)outv)[dst] = resid[dst] + g * v;
                }
            }
        }
    }
}

// ---------------------------------------------------------------------------
// 5) MFMA windowed attention. Block = 4 waves = 4 heads of one window.
// ---------------------------------------------------------------------------
__global__ __launch_bounds__(256)
void attn_mfma(const u16* __restrict__ qkv, const float* __restrict__ bias_table,
               u16* __restrict__ out)
{
    const int w    = blockIdx.x;          // chunk-local: b_local*64 + wi
    const int hg   = blockIdx.y;          // 0..3
    const int wave = threadIdx.x >> 6;
    const int lane = threadIdx.x & 63;
    const int h    = hg * 4 + wave;
    const int wi   = w & 63;
    const int quad = lane >> 4;
    const int mrow = lane & 15;

    __shared__ u16 sP[4][64][72];      // per-wave P (bf16), pitch 72 (144B rows)
    __shared__ u16 sVt[4][32][72];     // per-wave V^T (bf16)
    __shared__ float sBias[4][169];    // per-wave head bias slice

    const u16* qb = qkv + (size_t)w * NWIN * 1536 + h * DHEAD;

    // stage per-head bias slice (strided global, L2-resident table)
    for (int e = lane; e < 169; e += 64)
        sBias[wave][e] = bias_table[e * NHEAD + h];

    // stage V transposed: rows 0..48 real, 49..63 zeroed
    #pragma unroll
    for (int rr = 0; rr < 4; ++rr) {
        int e = rr * 64 + lane;
        int r = e >> 2, d0 = (e & 3) * 8;
        u16x8 vv = {};
        if (e < 196)
            vv = *(const u16x8*)(qb + (size_t)r * 1536 + 1024 + d0);
        #pragma unroll
        for (int j = 0; j < 8; ++j)
            sVt[wave][d0 + j][r] = vv[j];
    }

    // Q/K fragments direct from global; pad rows (49..63) clamped to 48
    s16x8 qf[4], kf[4];
    #pragma unroll
    for (int t = 0; t < 4; ++t) {
        int r = t * 16 + mrow; if (r > 48) r = 48;
        qf[t] = *(const s16x8*)(qb + (size_t)r * 1536 + quad * 8);
        kf[t] = *(const s16x8*)(qb + (size_t)r * 1536 + 512 + quad * 8);
    }
    __syncthreads();   // sVt / sBias visible

    // S = Q K^T : S[m][n], m = tm*16+quad*4+i, n = tn*16+mrow
    f32x4 sacc[4][4] = {};
    #pragma unroll
    for (int tm = 0; tm < 4; ++tm)
        #pragma unroll
        for (int tn = 0; tn < 4; ++tn)
            sacc[tm][tn] = __builtin_amdgcn_mfma_f32_16x16x32_bf16(
                qf[tm], kf[tn], sacc[tm][tn], 0, 0, 0);

    const float scale = 0.17677669529663687f;   // 1/sqrt(32)
    const int wh = wi >> 3, ww = wi & 7;

    // per-lane key-side terms (constant across tm,i)
    int khA[4], kwA[4], rkA[4], nOK[4];
    #pragma unroll
    for (int tn = 0; tn < 4; ++tn) {
        int n = tn * 16 + mrow;
        nOK[tn] = (n < NWIN);
        int nc = n > 48 ? 48 : n;
        khA[tn] = nc / 7; kwA[tn] = nc - khA[tn] * 7;
        int gkh = wh * 7 + khA[tn], gkw = ww * 7 + kwA[tn];
        rkA[tn] = (gkh < 49 ? 0 : (gkh < 53 ? 1 : 2)) * 3
                + (gkw < 49 ? 0 : (gkw < 53 ? 1 : 2));
    }

    #pragma unroll
    for (int tm = 0; tm < 4; ++tm) {
        #pragma unroll
        for (int i = 0; i < 4; ++i) {
            int m = tm * 16 + quad * 4 + i;
            int mc = m > 48 ? 48 : m;            // garbage rows: keep idx bounded
            int qh = mc / 7, qw = mc - qh * 7;
            int gqh = wh * 7 + qh, gqw = ww * 7 + qw;
            int rq = (gqh < 49 ? 0 : (gqh < 53 ? 1 : 2)) * 3
                   + (gqw < 49 ? 0 : (gqw < 53 ? 1 : 2));
            float v[4];
            #pragma unroll
            for (int tn = 0; tn < 4; ++tn) {
                float s = sacc[tm][tn][i] * scale;
                s += sBias[wave][(qh - khA[tn] + 6) * 13 + (qw - kwA[tn] + 6)];
                if (rq != rkA[tn]) s -= 100.0f;
                v[tn] = nOK[tn] ? s : -1e30f;
            }
            float mx = fmaxf(fmaxf(v[0], v[1]), fmaxf(v[2], v[3]));
            mx = fmaxf(mx, __shfl_xor(mx, 1));
            mx = fmaxf(mx, __shfl_xor(mx, 2));
            mx = fmaxf(mx, __shfl_xor(mx, 4));
            mx = fmaxf(mx, __shfl_xor(mx, 8));
            float p0 = __expf(v[0] - mx), p1 = __expf(v[1] - mx);
            float p2 = __expf(v[2] - mx), p3 = __expf(v[3] - mx);
            float sum = p0 + p1 + p2 + p3;
            sum += __shfl_xor(sum, 1);
            sum += __shfl_xor(sum, 2);
            sum += __shfl_xor(sum, 4);
            sum += __shfl_xor(sum, 8);
            float inv = 1.0f / sum;
            float pp[4] = { p0 * inv, p1 * inv, p2 * inv, p3 * inv };
            // pack (n, n+1) bf16 pairs via neighbor shfl; even-mrow lanes write
            #pragma unroll
            for (int tn = 0; tn < 4; ++tn) {
                float po = __shfl_xor(pp[tn], 1);
                if (!(mrow & 1)) {
                    unsigned int pk = (unsigned int)f2bf(pp[tn])
                                    | ((unsigned int)f2bf(po) << 16);
                    *(unsigned int*)&sP[wave][m][tn * 16 + mrow] = pk;
                }
            }
        }
    }
    __syncthreads();   // sP ready

    // O^T[d][m] = sum_n V[n][d] * P[m][n] ; A = V^T frags, B = P frags
    f32x4 oacc[2][4] = {};
    #pragma unroll
    for (int ks = 0; ks < 2; ++ks) {
        s16x8 vf[2], pf[4];
        #pragma unroll
        for (int td = 0; td < 2; ++td)
            vf[td] = *(const s16x8*)&sVt[wave][td * 16 + mrow][ks * 32 + quad * 8];
        #pragma unroll
        for (int tm = 0; tm < 4; ++tm)
            pf[tm] = *(const s16x8*)&sP[wave][tm * 16 + mrow][ks * 32 + quad * 8];
        #pragma unroll
        for (int td = 0; td < 2; ++td)
            #pragma unroll
            for (int tm = 0; tm < 4; ++tm)
                oacc[td][tm] = __builtin_amdgcn_mfma_f32_16x16x32_bf16(
                    vf[td], pf[tm], oacc[td][tm], 0, 0, 0);
    }

    // store: lane holds O^T[d = td*16+quad*4+i][m = tm*16+mrow]
    #pragma unroll
    for (int tm = 0; tm < 4; ++tm) {
        int m = tm * 16 + mrow;
        if (m < NWIN) {
            u16* orow = out + ((size_t)(w * NWIN + m)) * C_DIM + h * DHEAD;
            #pragma unroll
            for (int td = 0; td < 2; ++td) {
                u16x4 ov;
                #pragma unroll
                for (int i = 0; i < 4; ++i) ov[i] = f2bf(oacc[td][tm][i]);
                *(u16x4*)(orow + td * 16 + quad * 4) = ov;
            }
        }
    }
}

// ---------------------------------------------------------------------------
// fp32 I/O, bf16 compute core. x2 lives in d_out.
// Workspace: two aliased slots (lifetimes disjoint):
//   slotS = winC -> aoC -> h2C   (CB * 3136 * 512  * 2B per batch)
//   slotL = qkvC -> ffiC         (CB * 3136 * 2048 * 2B per batch)
// CB tiers: 4 (70.7 MB, proven) / 8 (134.9 MB) / 16 (263.4 MB, single chunk).
// ---------------------------------------------------------------------------
extern "C" void kernel_launch(void* const* d_in, const int* in_sizes, int n_in,
                              void* d_out, int out_size, void* d_ws, size_t ws_size,
                              hipStream_t stream)
{
    const float* x       = (const float*)d_in[0];
    const float* emb     = (const float*)d_in[1];
    const float* adaLN_w = (const float*)d_in[2];
    const float* adaLN_b = (const float*)d_in[3];
    const float* qkv_w   = (const float*)d_in[4];
    const float* qkv_b   = (const float*)d_in[5];
    const float* proj_w  = (const float*)d_in[6];
    const float* proj_b  = (const float*)d_in[7];
    const float* relb    = (const float*)d_in[8];
    const float* ff_w1   = (const float*)d_in[9];
    const float* ff_b1   = (const float*)d_in[10];
    const float* ff_w2   = (const float*)d_in[11];
    const float* ff_b2   = (const float*)d_in[12];
    float* outp = (float*)d_out;

    char* ws = (char*)d_ws;
    float* mod   = (float*)(ws + 0);                  //    196,608 B
    u16* wT_qkv  = (u16*)(ws + 196608);               //  1,572,864 B
    u16* wT_proj = (u16*)(ws + 1769472);              //    524,288 B
    u16* wT_ff1  = (u16*)(ws + 2293760);              //  2,097,152 B
    u16* wT_ff2  = (u16*)(ws + 4390912);              //  2,097,152 B
    char* slots  = ws + 6488064;

    const size_t perB_S = (size_t)L_TOK * C_DIM * sizeof(u16);   //  3,211,264
    const size_t perB_L = (size_t)L_TOK * MLP_DIM * sizeof(u16); // 12,845,056

    int CB = 4;   // 70,713,344 B total (proven fit)
    if (ws_size >= 6488064 + 8  * (perB_S + perB_L)) CB = 8;
    if (ws_size >= 6488064 + 16 * (perB_S + perB_L)) CB = 16;

    const int nChunks   = B_SZ / CB;
    const int chunkRows = CB * L_TOK;
    const int nrb       = chunkRows / 128;            // row-blocks per chunk
    u16* slotS = (u16*)slots;                         // winC / aoC / h2C
    u16* slotL = (u16*)(slots + (size_t)CB * perB_S); // qkvC / ffiC

    // prolog (once)
    mod_kernel<<<dim3(12, 16), dim3(256), 0, stream>>>(emb, adaLN_w, adaLN_b, mod);
    transpose_kernel<<<dim3(16, 48), dim3(32, 32), 0, stream>>>(qkv_w,  wT_qkv, 512, 1536);
    transpose_kernel<<<dim3(16, 16), dim3(32, 32), 0, stream>>>(proj_w, wT_proj, 512, 512);
    transpose_kernel<<<dim3(16, 64), dim3(32, 32), 0, stream>>>(ff_w1,  wT_ff1, 512, 2048);
    transpose_kernel<<<dim3(64, 16), dim3(32, 32), 0, stream>>>(ff_w2,  wT_ff2, 2048, 512);

    for (int c = 0; c < nChunks; ++c) {
        int row0 = c * chunkRows;
        // LN1 + modulate + shift + window partition: x[row0..] -> slotS (winC)
        ln_kernel<1><<<dim3(chunkRows / 4), dim3(256), 0, stream>>>(
            x, mod, slotS, 0, 512, row0);
        // qkv GEMM: winC @ wT_qkv -> slotL (qkvC)
        gemm128<0><<<dim3(nrb * 12), dim3(256), 0, stream>>>(
            slotS, wT_qkv, qkv_b, slotL, nullptr, mod, 1536, 512, 0, 12);
        // attention (MFMA): qkvC -> slotS (aoC; winC is dead)
        attn_mfma<<<dim3(CB * 64, 4), dim3(256), 0, stream>>>(slotL, relb, slotS);
        // proj + window reverse + unshift + residual(x) -> d_out (x2, fp32)
        gemm128<2><<<dim3(nrb * 4), dim3(256), 0, stream>>>(
            slotS, wT_proj, proj_b, outp, x, mod, 512, 512, row0, 4);
        // LN2 + modulate: d_out[row0..] -> slotS (h2C; aoC is dead)
        ln_kernel<0><<<dim3(chunkRows / 4), dim3(256), 0, stream>>>(
            outp, mod, slotS, 1536, 2048, row0);
        // FF1 + GELU: h2C -> slotL (ffiC; qkvC is dead)
        gemm128<1><<<dim3(nrb * 16), dim3(256), 0, stream>>>(
            slotS, wT_ff1, ff_b1, slotL, nullptr, mod, 2048, 512, 0, 16);
        // FF2 + residual(x2) -> d_out
        gemm128<3><<<dim3(nrb * 4), dim3(256), 0, stream>>>(
            slotL, wT_ff2, ff_b2, outp, outp, mod, 512, 2048, row0, 4);
    }
}

// Round 7
// 1013.396 us; speedup vs baseline: 1.0971x; 1.0971x over previous
//
#include <hip/hip_runtime.h>
#include <cmath>

typedef unsigned short u16;
typedef unsigned short u16x2 __attribute__((ext_vector_type(2)));
typedef unsigned short u16x4 __attribute__((ext_vector_type(4)));
typedef unsigned short u16x8 __attribute__((ext_vector_type(8)));
typedef short s16x8 __attribute__((ext_vector_type(8)));
typedef float f32x4 __attribute__((ext_vector_type(4)));
typedef float f32x2 __attribute__((ext_vector_type(2)));

#define B_SZ 16
#define HW 56
#define L_TOK 3136      // 56*56
#define C_DIM 512
#define NHEAD 16
#define DHEAD 32
#define WS7 7
#define NWIN 49
#define ROWS_TOTAL 50176   // 16*3136
#define MLP_DIM 2048

__device__ __forceinline__ float bf2f(u16 u) {
    union { unsigned int i; float f; } z;
    z.i = ((unsigned int)u) << 16;
    return z.f;
}
__device__ __forceinline__ u16 f2bf(float f) {
    union { float f; unsigned int i; } z;
    z.f = f;
    unsigned int r = z.i + 0x7fffu + ((z.i >> 16) & 1u);
    return (u16)(r >> 16);
}

// async global->LDS, 16B per lane; LDS dest = wave-uniform base + lane*16
__device__ __forceinline__ void gl_lds16(const u16* g, u16* l) {
    __builtin_amdgcn_global_load_lds(
        (const __attribute__((address_space(1))) unsigned int*)g,
        (__attribute__((address_space(3))) unsigned int*)l,
        16, 0, 0);
}

// ---------------------------------------------------------------------------
// 1) mod = silu(emb) @ adaLN_w + adaLN_b -> fp32 [16,3072]
// ---------------------------------------------------------------------------
__global__ __launch_bounds__(256)
void mod_kernel(const float* __restrict__ emb, const float* __restrict__ w,
                const float* __restrict__ bias, float* __restrict__ mod)
{
    int b = blockIdx.y;
    int o = blockIdx.x * 256 + threadIdx.x;
    __shared__ float se[512];
    for (int i = threadIdx.x; i < 512; i += 256) {
        float e = emb[b * 512 + i];
        se[i] = e / (1.0f + expf(-e));
    }
    __syncthreads();
    float acc = bias[o];
    #pragma unroll 8
    for (int k = 0; k < 512; ++k)
        acc += se[k] * w[(size_t)k * 3072 + o];
    mod[b * 3072 + o] = acc;
}

// ---------------------------------------------------------------------------
// 2) weight transpose + bf16 cast: Wt[n][k] = bf16(W[k][n])
// ---------------------------------------------------------------------------
__global__ __launch_bounds__(1024)
void transpose_kernel(const float* __restrict__ W, u16* __restrict__ Wt, int K, int N)
{
    __shared__ float tile[32][33];
    int k0 = blockIdx.x * 32, n0 = blockIdx.y * 32;
    tile[threadIdx.y][threadIdx.x] = W[(size_t)(k0 + threadIdx.y) * N + (n0 + threadIdx.x)];
    __syncthreads();
    Wt[(size_t)(n0 + threadIdx.y) * K + (k0 + threadIdx.x)] = f2bf(tile[threadIdx.x][threadIdx.y]);
}

// ---------------------------------------------------------------------------
// 3) LN + adaLN modulate; wave-per-row (4 rows/block), no LDS / syncthreads.
// ---------------------------------------------------------------------------
template<int WINDOWED>
__global__ __launch_bounds__(256)
void ln_kernel(const float* __restrict__ xin, const float* __restrict__ mod,
               u16* __restrict__ out, int shOff, int scOff, int rowBase)
{
    int wv   = threadIdx.x >> 6;
    int lane = threadIdx.x & 63;
    int rbl = blockIdx.x * 4 + wv;        // chunk-local row
    int rb  = rbl + rowBase;              // global sequence row
    int b = rb / L_TOK, l = rb - b * L_TOK;
    const float* xr = xin + (size_t)rb * C_DIM;
    int c0 = lane * 8;
    f32x4 u0 = *(const f32x4*)(xr + c0);
    f32x4 u1 = *(const f32x4*)(xr + c0 + 4);
    float s = u0.x + u0.y + u0.z + u0.w + u1.x + u1.y + u1.z + u1.w;
    float q = u0.x*u0.x + u0.y*u0.y + u0.z*u0.z + u0.w*u0.w
            + u1.x*u1.x + u1.y*u1.y + u1.z*u1.z + u1.w*u1.w;
    #pragma unroll
    for (int off = 32; off > 0; off >>= 1) {
        s += __shfl_xor(s, off);
        q += __shfl_xor(q, off);
    }
    float mu = s * (1.0f / 512.0f);
    float var = q * (1.0f / 512.0f) - mu * mu;
    float rstd = rsqrtf(var + 1e-6f);
    const float* mb = mod + b * 3072;
    f32x4 sc0 = *(const f32x4*)(mb + scOff + c0);
    f32x4 sc1 = *(const f32x4*)(mb + scOff + c0 + 4);
    f32x4 sh0 = *(const f32x4*)(mb + shOff + c0);
    f32x4 sh1 = *(const f32x4*)(mb + shOff + c0 + 4);
    float y[8];
    y[0] = (u0.x - mu) * rstd * (1.0f + sc0.x) + sh0.x;
    y[1] = (u0.y - mu) * rstd * (1.0f + sc0.y) + sh0.y;
    y[2] = (u0.z - mu) * rstd * (1.0f + sc0.z) + sh0.z;
    y[3] = (u0.w - mu) * rstd * (1.0f + sc0.w) + sh0.w;
    y[4] = (u1.x - mu) * rstd * (1.0f + sc1.x) + sh1.x;
    y[5] = (u1.y - mu) * rstd * (1.0f + sc1.y) + sh1.y;
    y[6] = (u1.z - mu) * rstd * (1.0f + sc1.z) + sh1.z;
    y[7] = (u1.w - mu) * rstd * (1.0f + sc1.w) + sh1.w;
    size_t drow;
    if (WINDOWED) {
        int hh = l / HW, ww = l - hh * HW;
        int hs = hh - 3; if (hs < 0) hs += HW;
        int ws2 = ww - 3; if (ws2 < 0) ws2 += HW;
        int wi = (hs / WS7) * 8 + (ws2 / WS7);
        int n  = (hs % WS7) * WS7 + (ws2 % WS7);
        int b_local = rbl / L_TOK;
        drow = (size_t)((b_local * 64 + wi) * NWIN + n);
    } else {
        drow = (size_t)rbl;
    }
    u16x8 o;
    #pragma unroll
    for (int i = 0; i < 8; ++i) o[i] = f2bf(y[i]);
    *(u16x8*)(out + drow * C_DIM + c0) = o;
}

// ---------------------------------------------------------------------------
// 4) GEMM: C[M,N] = A[M,K] @ Bt[N,K]^T + bias
//    256x256 tile, BK=32, 8 waves (512 thr), wave = 64x128 sub-tile,
//    acc[4][8] mfma_f32_16x16x32_bf16.
//    WHY 256: rounds 1-6 showed FF2 pinned at ~260us across ALL schedules;
//    staged traffic (BM+BN)*K*2B*blocks = 1.57GB at 128^2 ran at ~6 TB/s =
//    the L3/fabric ceiling (L2 thrashes; FETCH showed only 183MB from HBM).
//    256^2 halves staged bytes and lets the BN=256 weight panels go
//    L2-resident.  Depth-3 pipeline, 4 static LDS buffers (128KB), counted
//    vmcnt(8); per-wave invariant unchanged (4 gl_lds per STAGE).
//    Both-sides chunk swizzle (verified r6: conflicts -> 0).
//    Requires M%256==0, nt=K/32 multiple of 4 >= 8 (all shapes qualify).
// ---------------------------------------------------------------------------
template<int EPI>
__global__ __launch_bounds__(512, 2)
void gemm256(const u16* __restrict__ A, const u16* __restrict__ Bt,
             const float* __restrict__ bias, void* __restrict__ outv,
             const float* __restrict__ resid, const float* __restrict__ mod,
             int N, int K, int rowOffset, int nyb)
{
    __shared__ u16 sA[4][256][32];   // 64 KB
    __shared__ u16 sB[4][256][32];   // 64 KB
    const int tid  = threadIdx.x;
    const int lane = tid & 63;
    const int wave = tid >> 6;       // 0..7
    const int wm = wave >> 1;        // 0..3 : row group (64 rows)
    const int wn = wave & 1;         // 0..1 : col group (128 cols)
    const int quad = lane >> 4;
    const int mrow = lane & 15;

    // bijective XCD-chunked swizzle (m204), col-block fastest within chunk
    const int nwg  = gridDim.x;
    const int orig = blockIdx.x;
    const int xq = nwg >> 3, xr = nwg & 7;
    const int xcd = orig & 7, xidx = orig >> 3;
    const int wgid = (xcd < xr ? xcd * (xq + 1)
                               : xr * (xq + 1) + (xcd - xr) * xq) + xidx;
    const int bx = wgid / nyb;
    const int by = wgid - bx * nyb;
    const int rowBase = bx * 256;
    const int colBase = by * 256;

    const int r0   = wave * 32;      // wave stages A rows/B rows [r0, r0+32)
    const int lrow = lane >> 2;
    // pre-swizzled global source chunk (both-sides swizzle, rule #21)
    const int lcol = ((lane & 3) ^ ((lane >> 3) & 3)) * 8;
    const u16* gA = A  + (size_t)(rowBase + r0 + lrow) * K + lcol;
    const u16* gB = Bt + (size_t)(colBase + r0 + lrow) * K + lcol;
    const size_t gstep = (size_t)16 * K;
    // read-side physical chunk for logical k-chunk 'quad'
    const int cq = (quad ^ ((mrow >> 1) & 3)) * 8;

    f32x4 acc[4][8] = {};
    const int nt = K >> 5;   // multiple of 4, >= 8

#define STAGE(bi, kk) do {                                 \
    gl_lds16(gA + (kk),         &sA[bi][r0][0]);           \
    gl_lds16(gA + (kk) + gstep, &sA[bi][r0 + 16][0]);      \
    gl_lds16(gB + (kk),         &sB[bi][r0][0]);           \
    gl_lds16(gB + (kk) + gstep, &sB[bi][r0 + 16][0]);      \
} while (0)

#define COMPUTE(bi)                                                        \
    {                                                                      \
        s16x8 af[4], bg[8];                                                \
        _Pragma("unroll")                                                  \
        for (int tt = 0; tt < 4; ++tt)                                     \
            af[tt] = *(const s16x8*)&sA[bi][wm * 64 + tt * 16 + mrow][cq]; \
        _Pragma("unroll")                                                  \
        for (int tn = 0; tn < 8; ++tn)                                     \
            bg[tn] = *(const s16x8*)&sB[bi][wn * 128 + tn * 16 + mrow][cq];\
        _Pragma("unroll")                                                  \
        for (int tm = 0; tm < 4; ++tm)                                     \
            _Pragma("unroll")                                              \
            for (int tn = 0; tn < 8; ++tn)                                 \
                acc[tm][tn] = __builtin_amdgcn_mfma_f32_16x16x32_bf16(     \
                    af[tm], bg[tn], acc[tm][tn], 0, 0, 0);                 \
    }

#define WAIT8() asm volatile("s_waitcnt vmcnt(8) lgkmcnt(0)" ::: "memory")
#define WAIT4() asm volatile("s_waitcnt vmcnt(4) lgkmcnt(0)" ::: "memory")
#define WAIT0() asm volatile("s_waitcnt vmcnt(0) lgkmcnt(0)" ::: "memory")
#define BAR()   do { __builtin_amdgcn_s_barrier();                         \
                     __builtin_amdgcn_sched_barrier(0); } while (0)

    STAGE(0, 0);
    STAGE(1, 32);
    STAGE(2, 64);
    // invariant at each phase top: tiles t, t+1, t+2 in flight (12 loads/wave)

    for (int t = 0; t < nt - 4; t += 4) {
        // compute tile t (buf 0); stage tile t+3 -> buf 3 (freed last phase)
        WAIT8(); BAR(); STAGE(3, (t + 3) << 5); COMPUTE(0);
        WAIT8(); BAR(); STAGE(0, (t + 4) << 5); COMPUTE(1);
        WAIT8(); BAR(); STAGE(1, (t + 5) << 5); COMPUTE(2);
        WAIT8(); BAR(); STAGE(2, (t + 6) << 5); COMPUTE(3);
    }
    // t = nt-4: stage final tile nt-1 into buffer 3
    WAIT8(); BAR(); STAGE(3, (nt - 1) << 5); COMPUTE(0);
    // t = nt-3: 12 outstanding -> oldest 4 = tile nt-3
    WAIT8(); BAR(); COMPUTE(1);
    // t = nt-2: 8 outstanding
    WAIT4(); BAR(); COMPUTE(2);
    // t = nt-1: drain
    WAIT0(); BAR(); COMPUTE(3);

#undef STAGE
#undef COMPUTE
#undef WAIT8
#undef WAIT4
#undef WAIT0
#undef BAR

    #pragma unroll
    for (int tm = 0; tm < 4; ++tm) {
        #pragma unroll
        for (int tn = 0; tn < 8; ++tn) {
            int col = colBase + wn * 128 + tn * 16 + mrow;
            float bv = bias[col];
            #pragma unroll
            for (int i = 0; i < 4; ++i) {
                int r = rowBase + wm * 64 + tm * 16 + quad * 4 + i; // chunk-local
                float v = acc[tm][tn][i] + bv;
                if constexpr (EPI == 0) {
                    ((u16*)outv)[(size_t)r * N + col] = f2bf(v);
                } else if constexpr (EPI == 1) {
                    float g = 0.5f * v * (1.0f + erff(v * 0.70710678118654752f));
                    ((u16*)outv)[(size_t)r * N + col] = f2bf(g);
                } else if constexpr (EPI == 2) {
                    int rg = r + rowOffset;        // global window-layout row
                    int b = rg / L_TOK;
                    int rem = rg - b * L_TOK;
                    int wi = rem / NWIN;
                    int n  = rem - wi * NWIN;
                    int hs  = (wi >> 3) * WS7 + n / WS7;
                    int ws2 = (wi & 7) * WS7 + n % WS7;
                    int hh = hs + 3;  if (hh >= HW)  hh -= HW;
                    int ww = ws2 + 3; if (ww >= HW)  ww -= HW;
                    size_t dst = ((size_t)(b * L_TOK + hh * HW + ww)) * C_DIM + col;
                    float g = mod[b * 3072 + 1024 + col];
                    ((float*)outv)[dst] = resid[dst] + g * v;
                } else {  // EPI == 3
                    int rg = r + rowOffset;        // global sequence row
                    int b = rg / L_TOK;
                    size_t dst = (size_t)rg * C_DIM + col;
                    float g = mod[b * 3072 + 2560 + col];
                    ((float*)outv)[dst] = resid[dst] + g * v;
                }
            }
        }
    }
}

// ---------------------------------------------------------------------------
// 5) MFMA windowed attention. Block = 4 waves = 4 heads of one window.
// ---------------------------------------------------------------------------
__global__ __launch_bounds__(256)
void attn_mfma(const u16* __restrict__ qkv, const float* __restrict__ bias_table,
               u16* __restrict__ out)
{
    const int w    = blockIdx.x;          // chunk-local: b_local*64 + wi
    const int hg   = blockIdx.y;          // 0..3
    const int wave = threadIdx.x >> 6;
    const int lane = threadIdx.x & 63;
    const int h    = hg * 4 + wave;
    const int wi   = w & 63;
    const int quad = lane >> 4;
    const int mrow = lane & 15;

    __shared__ u16 sP[4][64][72];      // per-wave P (bf16), pitch 72 (144B rows)
    __shared__ u16 sVt[4][32][72];     // per-wave V^T (bf16)
    __shared__ float sBias[4][169];    // per-wave head bias slice

    const u16* qb = qkv + (size_t)w * NWIN * 1536 + h * DHEAD;

    // stage per-head bias slice (strided global, L2-resident table)
    for (int e = lane; e < 169; e += 64)
        sBias[wave][e] = bias_table[e * NHEAD + h];

    // stage V transposed: rows 0..48 real, 49..63 zeroed
    #pragma unroll
    for (int rr = 0; rr < 4; ++rr) {
        int e = rr * 64 + lane;
        int r = e >> 2, d0 = (e & 3) * 8;
        u16x8 vv = {};
        if (e < 196)
            vv = *(const u16x8*)(qb + (size_t)r * 1536 + 1024 + d0);
        #pragma unroll
        for (int j = 0; j < 8; ++j)
            sVt[wave][d0 + j][r] = vv[j];
    }

    // Q/K fragments direct from global; pad rows (49..63) clamped to 48
    s16x8 qf[4], kf[4];
    #pragma unroll
    for (int t = 0; t < 4; ++t) {
        int r = t * 16 + mrow; if (r > 48) r = 48;
        qf[t] = *(const s16x8*)(qb + (size_t)r * 1536 + quad * 8);
        kf[t] = *(const s16x8*)(qb + (size_t)r * 1536 + 512 + quad * 8);
    }
    __syncthreads();   // sVt / sBias visible

    // S = Q K^T : S[m][n], m = tm*16+quad*4+i, n = tn*16+mrow
    f32x4 sacc[4][4] = {};
    #pragma unroll
    for (int tm = 0; tm < 4; ++tm)
        #pragma unroll
        for (int tn = 0; tn < 4; ++tn)
            sacc[tm][tn] = __builtin_amdgcn_mfma_f32_16x16x32_bf16(
                qf[tm], kf[tn], sacc[tm][tn], 0, 0, 0);

    const float scale = 0.17677669529663687f;   // 1/sqrt(32)
    const int wh = wi >> 3, ww = wi & 7;

    // per-lane key-side terms (constant across tm,i)
    int khA[4], kwA[4], rkA[4], nOK[4];
    #pragma unroll
    for (int tn = 0; tn < 4; ++tn) {
        int n = tn * 16 + mrow;
        nOK[tn] = (n < NWIN);
        int nc = n > 48 ? 48 : n;
        khA[tn] = nc / 7; kwA[tn] = nc - khA[tn] * 7;
        int gkh = wh * 7 + khA[tn], gkw = ww * 7 + kwA[tn];
        rkA[tn] = (gkh < 49 ? 0 : (gkh < 53 ? 1 : 2)) * 3
                + (gkw < 49 ? 0 : (gkw < 53 ? 1 : 2));
    }

    #pragma unroll
    for (int tm = 0; tm < 4; ++tm) {
        #pragma unroll
        for (int i = 0; i < 4; ++i) {
            int m = tm * 16 + quad * 4 + i;
            int mc = m > 48 ? 48 : m;            // garbage rows: keep idx bounded
            int qh = mc / 7, qw = mc - qh * 7;
            int gqh = wh * 7 + qh, gqw = ww * 7 + qw;
            int rq = (gqh < 49 ? 0 : (gqh < 53 ? 1 : 2)) * 3
                   + (gqw < 49 ? 0 : (gqw < 53 ? 1 : 2));
            float v[4];
            #pragma unroll
            for (int tn = 0; tn < 4; ++tn) {
                float s = sacc[tm][tn][i] * scale;
                s += sBias[wave][(qh - khA[tn] + 6) * 13 + (qw - kwA[tn] + 6)];
                if (rq != rkA[tn]) s -= 100.0f;
                v[tn] = nOK[tn] ? s : -1e30f;
            }
            float mx = fmaxf(fmaxf(v[0], v[1]), fmaxf(v[2], v[3]));
            mx = fmaxf(mx, __shfl_xor(mx, 1));
            mx = fmaxf(mx, __shfl_xor(mx, 2));
            mx = fmaxf(mx, __shfl_xor(mx, 4));
            mx = fmaxf(mx, __shfl_xor(mx, 8));
            float p0 = __expf(v[0] - mx), p1 = __expf(v[1] - mx);
            float p2 = __expf(v[2] - mx), p3 = __expf(v[3] - mx);
            float sum = p0 + p1 + p2 + p3;
            sum += __shfl_xor(sum, 1);
            sum += __shfl_xor(sum, 2);
            sum += __shfl_xor(sum, 4);
            sum += __shfl_xor(sum, 8);
            float inv = 1.0f / sum;
            float pp[4] = { p0 * inv, p1 * inv, p2 * inv, p3 * inv };
            // pack (n, n+1) bf16 pairs via neighbor shfl; even-mrow lanes write
            #pragma unroll
            for (int tn = 0; tn < 4; ++tn) {
                float po = __shfl_xor(pp[tn], 1);
                if (!(mrow & 1)) {
                    unsigned int pk = (unsigned int)f2bf(pp[tn])
                                    | ((unsigned int)f2bf(po) << 16);
                    *(unsigned int*)&sP[wave][m][tn * 16 + mrow] = pk;
                }
            }
        }
    }
    __syncthreads();   // sP ready

    // O^T[d][m] = sum_n V[n][d] * P[m][n] ; A = V^T frags, B = P frags
    f32x4 oacc[2][4] = {};
    #pragma unroll
    for (int ks = 0; ks < 2; ++ks) {
        s16x8 vf[2], pf[4];
        #pragma unroll
        for (int td = 0; td < 2; ++td)
            vf[td] = *(const s16x8*)&sVt[wave][td * 16 + mrow][ks * 32 + quad * 8];
        #pragma unroll
        for (int tm = 0; tm < 4; ++tm)
            pf[tm] = *(const s16x8*)&sP[wave][tm * 16 + mrow][ks * 32 + quad * 8];
        #pragma unroll
        for (int td = 0; td < 2; ++td)
            #pragma unroll
            for (int tm = 0; tm < 4; ++tm)
                oacc[td][tm] = __builtin_amdgcn_mfma_f32_16x16x32_bf16(
                    vf[td], pf[tm], oacc[td][tm], 0, 0, 0);
    }

    // store: lane holds O^T[d = td*16+quad*4+i][m = tm*16+mrow]
    #pragma unroll
    for (int tm = 0; tm < 4; ++tm) {
        int m = tm * 16 + mrow;
        if (m < NWIN) {
            u16* orow = out + ((size_t)(w * NWIN + m)) * C_DIM + h * DHEAD;
            #pragma unroll
            for (int td = 0; td < 2; ++td) {
                u16x4 ov;
                #pragma unroll
                for (int i = 0; i < 4; ++i) ov[i] = f2bf(oacc[td][tm][i]);
                *(u16x4*)(orow + td * 16 + quad * 4) = ov;
            }
        }
    }
}

// ---------------------------------------------------------------------------
// fp32 I/O, bf16 compute core. x2 lives in d_out.
// Workspace: two aliased slots (lifetimes disjoint):
//   slotS = winC -> aoC -> h2C   (CB * 3136 * 512  * 2B per batch)
//   slotL = qkvC -> ffiC         (CB * 3136 * 2048 * 2B per batch)
// CB tiers: 4 (70.7 MB, proven) / 8 (134.9 MB) / 16 (263.4 MB, single chunk).
// ---------------------------------------------------------------------------
extern "C" void kernel_launch(void* const* d_in, const int* in_sizes, int n_in,
                              void* d_out, int out_size, void* d_ws, size_t ws_size,
                              hipStream_t stream)
{
    const float* x       = (const float*)d_in[0];
    const float* emb     = (const float*)d_in[1];
    const float* adaLN_w = (const float*)d_in[2];
    const float* adaLN_b = (const float*)d_in[3];
    const float* qkv_w   = (const float*)d_in[4];
    const float* qkv_b   = (const float*)d_in[5];
    const float* proj_w  = (const float*)d_in[6];
    const float* proj_b  = (const float*)d_in[7];
    const float* relb    = (const float*)d_in[8];
    const float* ff_w1   = (const float*)d_in[9];
    const float* ff_b1   = (const float*)d_in[10];
    const float* ff_w2   = (const float*)d_in[11];
    const float* ff_b2   = (const float*)d_in[12];
    float* outp = (float*)d_out;

    char* ws = (char*)d_ws;
    float* mod   = (float*)(ws + 0);                  //    196,608 B
    u16* wT_qkv  = (u16*)(ws + 196608);               //  1,572,864 B
    u16* wT_proj = (u16*)(ws + 1769472);              //    524,288 B
    u16* wT_ff1  = (u16*)(ws + 2293760);              //  2,097,152 B
    u16* wT_ff2  = (u16*)(ws + 4390912);              //  2,097,152 B
    char* slots  = ws + 6488064;

    const size_t perB_S = (size_t)L_TOK * C_DIM * sizeof(u16);   //  3,211,264
    const size_t perB_L = (size_t)L_TOK * MLP_DIM * sizeof(u16); // 12,845,056

    int CB = 4;   // 70,713,344 B total (proven fit)
    if (ws_size >= 6488064 + 8  * (perB_S + perB_L)) CB = 8;
    if (ws_size >= 6488064 + 16 * (perB_S + perB_L)) CB = 16;

    const int nChunks   = B_SZ / CB;
    const int chunkRows = CB * L_TOK;
    const int nrb       = chunkRows / 256;            // 256-row blocks per chunk
    u16* slotS = (u16*)slots;                         // winC / aoC / h2C
    u16* slotL = (u16*)(slots + (size_t)CB * perB_S); // qkvC / ffiC

    // prolog (once)
    mod_kernel<<<dim3(12, 16), dim3(256), 0, stream>>>(emb, adaLN_w, adaLN_b, mod);
    transpose_kernel<<<dim3(16, 48), dim3(32, 32), 0, stream>>>(qkv_w,  wT_qkv, 512, 1536);
    transpose_kernel<<<dim3(16, 16), dim3(32, 32), 0, stream>>>(proj_w, wT_proj, 512, 512);
    transpose_kernel<<<dim3(16, 64), dim3(32, 32), 0, stream>>>(ff_w1,  wT_ff1, 512, 2048);
    transpose_kernel<<<dim3(64, 16), dim3(32, 32), 0, stream>>>(ff_w2,  wT_ff2, 2048, 512);

    for (int c = 0; c < nChunks; ++c) {
        int row0 = c * chunkRows;
        // LN1 + modulate + shift + window partition: x[row0..] -> slotS (winC)
        ln_kernel<1><<<dim3(chunkRows / 4), dim3(256), 0, stream>>>(
            x, mod, slotS, 0, 512, row0);
        // qkv GEMM: winC @ wT_qkv -> slotL (qkvC)   N=1536 -> 6 col-blocks
        gemm256<0><<<dim3(nrb * 6), dim3(512), 0, stream>>>(
            slotS, wT_qkv, qkv_b, slotL, nullptr, mod, 1536, 512, 0, 6);
        // attention (MFMA): qkvC -> slotS (aoC; winC is dead)
        attn_mfma<<<dim3(CB * 64, 4), dim3(256), 0, stream>>>(slotL, relb, slotS);
        // proj + window reverse + unshift + residual(x) -> d_out (x2, fp32)
        gemm256<2><<<dim3(nrb * 2), dim3(512), 0, stream>>>(
            slotS, wT_proj, proj_b, outp, x, mod, 512, 512, row0, 2);
        // LN2 + modulate: d_out[row0..] -> slotS (h2C; aoC is dead)
        ln_kernel<0><<<dim3(chunkRows / 4), dim3(256), 0, stream>>>(
            outp, mod, slotS, 1536, 2048, row0);
        // FF1 + GELU: h2C -> slotL (ffiC; qkvC is dead)   N=2048 -> 8
        gemm256<1><<<dim3(nrb * 8), dim3(512), 0, stream>>>(
            slotS, wT_ff1, ff_b1, slotL, nullptr, mod, 2048, 512, 0, 8);
        // FF2 + residual(x2) -> d_out   N=512 -> 2
        gemm256<3><<<dim3(nrb * 2), dim3(512), 0, stream>>>(
            slotL, wT_ff2, ff_b2, outp, outp, mod, 512, 2048, row0, 2);
    }
}

// Round 8
// 985.372 us; speedup vs baseline: 1.1283x; 1.0284x over previous
//
#include <hip/hip_runtime.h>
#include <cmath>

typedef unsigned short u16;
typedef unsigned short u16x2 __attribute__((ext_vector_type(2)));
typedef unsigned short u16x4 __attribute__((ext_vector_type(4)));
typedef unsigned short u16x8 __attribute__((ext_vector_type(8)));
typedef short s16x8 __attribute__((ext_vector_type(8)));
typedef float f32x4 __attribute__((ext_vector_type(4)));
typedef float f32x2 __attribute__((ext_vector_type(2)));

#define B_SZ 16
#define HW 56
#define L_TOK 3136      // 56*56
#define C_DIM 512
#define NHEAD 16
#define DHEAD 32
#define WS7 7
#define NWIN 49
#define ROWS_TOTAL 50176   // 16*3136
#define MLP_DIM 2048

__device__ __forceinline__ float bf2f(u16 u) {
    union { unsigned int i; float f; } z;
    z.i = ((unsigned int)u) << 16;
    return z.f;
}
__device__ __forceinline__ u16 f2bf(float f) {
    union { float f; unsigned int i; } z;
    z.f = f;
    unsigned int r = z.i + 0x7fffu + ((z.i >> 16) & 1u);
    return (u16)(r >> 16);
}

// async global->LDS, 16B per lane; LDS dest = wave-uniform base + lane*16
__device__ __forceinline__ void gl_lds16(const u16* g, u16* l) {
    __builtin_amdgcn_global_load_lds(
        (const __attribute__((address_space(1))) unsigned int*)g,
        (__attribute__((address_space(3))) unsigned int*)l,
        16, 0, 0);
}

// ---------------------------------------------------------------------------
// 1) mod = silu(emb) @ adaLN_w + adaLN_b -> fp32 [16,3072]
// ---------------------------------------------------------------------------
__global__ __launch_bounds__(256)
void mod_kernel(const float* __restrict__ emb, const float* __restrict__ w,
                const float* __restrict__ bias, float* __restrict__ mod)
{
    int b = blockIdx.y;
    int o = blockIdx.x * 256 + threadIdx.x;
    __shared__ float se[512];
    for (int i = threadIdx.x; i < 512; i += 256) {
        float e = emb[b * 512 + i];
        se[i] = e / (1.0f + expf(-e));
    }
    __syncthreads();
    float acc = bias[o];
    #pragma unroll 8
    for (int k = 0; k < 512; ++k)
        acc += se[k] * w[(size_t)k * 3072 + o];
    mod[b * 3072 + o] = acc;
}

// ---------------------------------------------------------------------------
// 2) weight transpose + bf16 cast: Wt[n][k] = bf16(W[k][n])
// ---------------------------------------------------------------------------
__global__ __launch_bounds__(1024)
void transpose_kernel(const float* __restrict__ W, u16* __restrict__ Wt, int K, int N)
{
    __shared__ float tile[32][33];
    int k0 = blockIdx.x * 32, n0 = blockIdx.y * 32;
    tile[threadIdx.y][threadIdx.x] = W[(size_t)(k0 + threadIdx.y) * N + (n0 + threadIdx.x)];
    __syncthreads();
    Wt[(size_t)(n0 + threadIdx.y) * K + (k0 + threadIdx.x)] = f2bf(tile[threadIdx.x][threadIdx.y]);
}

// ---------------------------------------------------------------------------
// 3) LN + adaLN modulate; wave-per-row (4 rows/block), no LDS / syncthreads.
// ---------------------------------------------------------------------------
template<int WINDOWED>
__global__ __launch_bounds__(256)
void ln_kernel(const float* __restrict__ xin, const float* __restrict__ mod,
               u16* __restrict__ out, int shOff, int scOff, int rowBase)
{
    int wv   = threadIdx.x >> 6;
    int lane = threadIdx.x & 63;
    int rbl = blockIdx.x * 4 + wv;        // chunk-local row
    int rb  = rbl + rowBase;              // global sequence row
    int b = rb / L_TOK, l = rb - b * L_TOK;
    const float* xr = xin + (size_t)rb * C_DIM;
    int c0 = lane * 8;
    f32x4 u0 = *(const f32x4*)(xr + c0);
    f32x4 u1 = *(const f32x4*)(xr + c0 + 4);
    float s = u0.x + u0.y + u0.z + u0.w + u1.x + u1.y + u1.z + u1.w;
    float q = u0.x*u0.x + u0.y*u0.y + u0.z*u0.z + u0.w*u0.w
            + u1.x*u1.x + u1.y*u1.y + u1.z*u1.z + u1.w*u1.w;
    #pragma unroll
    for (int off = 32; off > 0; off >>= 1) {
        s += __shfl_xor(s, off);
        q += __shfl_xor(q, off);
    }
    float mu = s * (1.0f / 512.0f);
    float var = q * (1.0f / 512.0f) - mu * mu;
    float rstd = rsqrtf(var + 1e-6f);
    const float* mb = mod + b * 3072;
    f32x4 sc0 = *(const f32x4*)(mb + scOff + c0);
    f32x4 sc1 = *(const f32x4*)(mb + scOff + c0 + 4);
    f32x4 sh0 = *(const f32x4*)(mb + shOff + c0);
    f32x4 sh1 = *(const f32x4*)(mb + shOff + c0 + 4);
    float y[8];
    y[0] = (u0.x - mu) * rstd * (1.0f + sc0.x) + sh0.x;
    y[1] = (u0.y - mu) * rstd * (1.0f + sc0.y) + sh0.y;
    y[2] = (u0.z - mu) * rstd * (1.0f + sc0.z) + sh0.z;
    y[3] = (u0.w - mu) * rstd * (1.0f + sc0.w) + sh0.w;
    y[4] = (u1.x - mu) * rstd * (1.0f + sc1.x) + sh1.x;
    y[5] = (u1.y - mu) * rstd * (1.0f + sc1.y) + sh1.y;
    y[6] = (u1.z - mu) * rstd * (1.0f + sc1.z) + sh1.z;
    y[7] = (u1.w - mu) * rstd * (1.0f + sc1.w) + sh1.w;
    size_t drow;
    if (WINDOWED) {
        int hh = l / HW, ww = l - hh * HW;
        int hs = hh - 3; if (hs < 0) hs += HW;
        int ws2 = ww - 3; if (ws2 < 0) ws2 += HW;
        int wi = (hs / WS7) * 8 + (ws2 / WS7);
        int n  = (hs % WS7) * WS7 + (ws2 % WS7);
        int b_local = rbl / L_TOK;
        drow = (size_t)((b_local * 64 + wi) * NWIN + n);
    } else {
        drow = (size_t)rbl;
    }
    u16x8 o;
    #pragma unroll
    for (int i = 0; i < 8; ++i) o[i] = f2bf(y[i]);
    *(u16x8*)(out + drow * C_DIM + c0) = o;
}

// ---------------------------------------------------------------------------
// 4) GEMM: C[M,N] = A[M,K] @ Bt[N,K]^T + bias
//    m201-style 8-phase 256x256 tile, BK=64, 8 waves (2M x 4N), per-wave
//    128x64 output, acc[8][4].  LDS = 2 dbuf x 2 K-half x {A,B} x 256x32
//    = 128 KB.  Half-tile FIFO S[i]: i>>2 = K-tile, i&3 = {A-kh0, B-kh0,
//    A-kh1, B-kh1}; buffer = (i>>2)&1.  Phase g stages S[g+6] (lookahead 6);
//    verified: S[g+6] overwrites S[g-2] whose last read finished >= 1
//    barrier before g, for all g mod 4.  vmcnt(4) at each K-tile head
//    retires all but the 2 newest entries (exactly the readiness
//    requirement); vmcnt(0) at the final K-tile.  Per phase: ds_read 4 or
//    8 x b128, stage 2 gl_lds, barrier, lgkmcnt(0), setprio(1), 16 MFMA,
//    setprio(0), barrier.  Both-sides chunk swizzle (verified r6/r7:
//    conflicts -> 0): physical chunk = logical ^ ((row>>1)&3).
//    Requires M%256==0, N%256==0, K%64==0 (all shapes qualify).
// ---------------------------------------------------------------------------
template<int EPI>
__global__ __launch_bounds__(512)
void gemm256(const u16* __restrict__ A, const u16* __restrict__ Bt,
             const float* __restrict__ bias, void* __restrict__ outv,
             const float* __restrict__ resid, const float* __restrict__ mod,
             int N, int K, int rowOffset, int nyb)
{
    __shared__ u16 sA[2][2][256][32];   // [buf][kh][row][chunk*8] = 64 KB
    __shared__ u16 sB[2][2][256][32];   // 64 KB
    const int tid  = threadIdx.x;
    const int lane = tid & 63;
    const int wave = tid >> 6;       // 0..7
    const int wm = wave >> 2;        // 0..1 : 128-row half
    const int wn = wave & 3;         // 0..3 : 64-col quarter
    const int quad = lane >> 4;
    const int mrow = lane & 15;

    // bijective XCD-chunked swizzle (m204), col-block fastest within chunk
    const int nwg  = gridDim.x;
    const int orig = blockIdx.x;
    const int xq = nwg >> 3, xr = nwg & 7;
    const int xcd = orig & 7, xidx = orig >> 3;
    const int wgid = (xcd < xr ? xcd * (xq + 1)
                               : xr * (xq + 1) + (xcd - xr) * xq) + xidx;
    const int bx = wgid / nyb;
    const int by = wgid - bx * nyb;
    const int rowBase = bx * 256;
    const int colBase = by * 256;

    // staging: wave stages rows [wave*32, wave*32+32) of the 256-row panel,
    // 2 gl_lds per half-tile (16 rows each).  Pre-swizzled global source.
    const int laneRow = lane >> 2;
    const int swz = ((lane & 3) ^ ((lane >> 3) & 3)) * 8;   // u16 offset
    const u16* pA0 = A  + (size_t)(rowBase + wave * 32 + laneRow) * K + swz;
    const u16* pA1 = pA0 + (size_t)16 * K;
    const u16* pB0 = Bt + (size_t)(colBase + wave * 32 + laneRow) * K + swz;
    const u16* pB1 = pB0 + (size_t)16 * K;
    // read-side physical chunk (u16 offset) for logical k-chunk 'quad'
    const int cq8 = (quad ^ ((mrow >> 1) & 3)) * 8;

    f32x4 acc[8][4] = {};
    s16x8 af[4], bg[4];
    const int NKT  = K >> 6;          // K-tiles of 64
    const int nkt4 = NKT << 2;        // total half-tile entries

#define STAGE_E(idx) do {                                            \
    const int _kt = (idx) >> 2, _e = (idx) & 3;                      \
    const int _buf = _kt & 1, _kh = _e >> 1;                         \
    const int _ko = _kt * 64 + _kh * 32;                             \
    if (_e & 1) {                                                    \
        gl_lds16(pB0 + _ko, &sB[_buf][_kh][wave * 32][0]);           \
        gl_lds16(pB1 + _ko, &sB[_buf][_kh][wave * 32 + 16][0]);      \
    } else {                                                         \
        gl_lds16(pA0 + _ko, &sA[_buf][_kh][wave * 32][0]);           \
        gl_lds16(pA1 + _ko, &sA[_buf][_kh][wave * 32 + 16][0]);      \
    }                                                                \
} while (0)

#define PHASE(_mh, _ks, _rdB) do {                                           \
    _Pragma("unroll")                                                        \
    for (int mi = 0; mi < 4; ++mi)                                           \
        af[mi] = *(const s16x8*)                                             \
            &sA[buf][_ks][wm * 128 + ((_mh) * 4 + mi) * 16 + mrow][cq8];     \
    if (_rdB) {                                                              \
        _Pragma("unroll")                                                    \
        for (int nf = 0; nf < 4; ++nf)                                       \
            bg[nf] = *(const s16x8*)                                         \
                &sB[buf][_ks][wn * 64 + nf * 16 + mrow][cq8];                \
    }                                                                        \
    if (sidx < nkt4) STAGE_E(sidx);                                          \
    ++sidx;                                                                  \
    __builtin_amdgcn_s_barrier();                                            \
    asm volatile("s_waitcnt lgkmcnt(0)" ::: "memory");                       \
    __builtin_amdgcn_sched_barrier(0);                                       \
    __builtin_amdgcn_s_setprio(1);                                           \
    _Pragma("unroll")                                                        \
    for (int mi = 0; mi < 4; ++mi)                                           \
        _Pragma("unroll")                                                    \
        for (int nf = 0; nf < 4; ++nf)                                       \
            acc[(_mh) * 4 + mi][nf] = __builtin_amdgcn_mfma_f32_16x16x32_bf16( \
                af[mi], bg[nf], acc[(_mh) * 4 + mi][nf], 0, 0, 0);           \
    __builtin_amdgcn_s_setprio(0);                                           \
    __builtin_amdgcn_s_barrier();                                            \
    __builtin_amdgcn_sched_barrier(0);                                       \
} while (0)

    int sidx = 6;
    // prologue: stage S[0..5] = kt0 fully + kt1 {A-kh0, B-kh0}
    STAGE_E(0); STAGE_E(1); STAGE_E(2); STAGE_E(3); STAGE_E(4); STAGE_E(5);

    for (int kt = 0; kt < NKT; ++kt) {
        const int buf = kt & 1;
        if (kt == NKT - 1)
            asm volatile("s_waitcnt vmcnt(0)" ::: "memory");
        else
            asm volatile("s_waitcnt vmcnt(4)" ::: "memory");
        __builtin_amdgcn_s_barrier();
        __builtin_amdgcn_sched_barrier(0);
        PHASE(0, 0, true);
        PHASE(1, 0, false);
        PHASE(0, 1, true);
        PHASE(1, 1, false);
    }
#undef STAGE_E
#undef PHASE

    #pragma unroll
    for (int mf = 0; mf < 8; ++mf) {
        #pragma unroll
        for (int nf = 0; nf < 4; ++nf) {
            int col = colBase + wn * 64 + nf * 16 + mrow;
            float bv = bias[col];
            #pragma unroll
            for (int i = 0; i < 4; ++i) {
                int r = rowBase + wm * 128 + mf * 16 + quad * 4 + i;  // chunk-local
                float v = acc[mf][nf][i] + bv;
                if constexpr (EPI == 0) {
                    ((u16*)outv)[(size_t)r * N + col] = f2bf(v);
                } else if constexpr (EPI == 1) {
                    float g = 0.5f * v * (1.0f + erff(v * 0.70710678118654752f));
                    ((u16*)outv)[(size_t)r * N + col] = f2bf(g);
                } else if constexpr (EPI == 2) {
                    int rg = r + rowOffset;        // global window-layout row
                    int b = rg / L_TOK;
                    int rem = rg - b * L_TOK;
                    int wi = rem / NWIN;
                    int n  = rem - wi * NWIN;
                    int hs  = (wi >> 3) * WS7 + n / WS7;
                    int ws2 = (wi & 7) * WS7 + n % WS7;
                    int hh = hs + 3;  if (hh >= HW)  hh -= HW;
                    int ww = ws2 + 3; if (ww >= HW)  ww -= HW;
                    size_t dst = ((size_t)(b * L_TOK + hh * HW + ww)) * C_DIM + col;
                    float g = mod[b * 3072 + 1024 + col];
                    ((float*)outv)[dst] = resid[dst] + g * v;
                } else {  // EPI == 3
                    int rg = r + rowOffset;        // global sequence row
                    int b = rg / L_TOK;
                    size_t dst = (size_t)rg * C_DIM + col;
                    float g = mod[b * 3072 + 2560 + col];
                    ((float*)outv)[dst] = resid[dst] + g * v;
                }
            }
        }
    }
}

// ---------------------------------------------------------------------------
// 5) MFMA windowed attention. Block = 4 waves = 4 heads of one window.
// ---------------------------------------------------------------------------
__global__ __launch_bounds__(256)
void attn_mfma(const u16* __restrict__ qkv, const float* __restrict__ bias_table,
               u16* __restrict__ out)
{
    const int w    = blockIdx.x;          // chunk-local: b_local*64 + wi
    const int hg   = blockIdx.y;          // 0..3
    const int wave = threadIdx.x >> 6;
    const int lane = threadIdx.x & 63;
    const int h    = hg * 4 + wave;
    const int wi   = w & 63;
    const int quad = lane >> 4;
    const int mrow = lane & 15;

    __shared__ u16 sP[4][64][72];      // per-wave P (bf16), pitch 72 (144B rows)
    __shared__ u16 sVt[4][32][72];     // per-wave V^T (bf16)
    __shared__ float sBias[4][169];    // per-wave head bias slice

    const u16* qb = qkv + (size_t)w * NWIN * 1536 + h * DHEAD;

    // stage per-head bias slice (strided global, L2-resident table)
    for (int e = lane; e < 169; e += 64)
        sBias[wave][e] = bias_table[e * NHEAD + h];

    // stage V transposed: rows 0..48 real, 49..63 zeroed
    #pragma unroll
    for (int rr = 0; rr < 4; ++rr) {
        int e = rr * 64 + lane;
        int r = e >> 2, d0 = (e & 3) * 8;
        u16x8 vv = {};
        if (e < 196)
            vv = *(const u16x8*)(qb + (size_t)r * 1536 + 1024 + d0);
        #pragma unroll
        for (int j = 0; j < 8; ++j)
            sVt[wave][d0 + j][r] = vv[j];
    }

    // Q/K fragments direct from global; pad rows (49..63) clamped to 48
    s16x8 qf[4], kf[4];
    #pragma unroll
    for (int t = 0; t < 4; ++t) {
        int r = t * 16 + mrow; if (r > 48) r = 48;
        qf[t] = *(const s16x8*)(qb + (size_t)r * 1536 + quad * 8);
        kf[t] = *(const s16x8*)(qb + (size_t)r * 1536 + 512 + quad * 8);
    }
    __syncthreads();   // sVt / sBias visible

    // S = Q K^T : S[m][n], m = tm*16+quad*4+i, n = tn*16+mrow
    f32x4 sacc[4][4] = {};
    #pragma unroll
    for (int tm = 0; tm < 4; ++tm)
        #pragma unroll
        for (int tn = 0; tn < 4; ++tn)
            sacc[tm][tn] = __builtin_amdgcn_mfma_f32_16x16x32_bf16(
                qf[tm], kf[tn], sacc[tm][tn], 0, 0, 0);

    const float scale = 0.17677669529663687f;   // 1/sqrt(32)
    const int wh = wi >> 3, ww = wi & 7;

    // per-lane key-side terms (constant across tm,i)
    int khA[4], kwA[4], rkA[4], nOK[4];
    #pragma unroll
    for (int tn = 0; tn < 4; ++tn) {
        int n = tn * 16 + mrow;
        nOK[tn] = (n < NWIN);
        int nc = n > 48 ? 48 : n;
        khA[tn] = nc / 7; kwA[tn] = nc - khA[tn] * 7;
        int gkh = wh * 7 + khA[tn], gkw = ww * 7 + kwA[tn];
        rkA[tn] = (gkh < 49 ? 0 : (gkh < 53 ? 1 : 2)) * 3
                + (gkw < 49 ? 0 : (gkw < 53 ? 1 : 2));
    }

    #pragma unroll
    for (int tm = 0; tm < 4; ++tm) {
        #pragma unroll
        for (int i = 0; i < 4; ++i) {
            int m = tm * 16 + quad * 4 + i;
            int mc = m > 48 ? 48 : m;            // garbage rows: keep idx bounded
            int qh = mc / 7, qw = mc - qh * 7;
            int gqh = wh * 7 + qh, gqw = ww * 7 + qw;
            int rq = (gqh < 49 ? 0 : (gqh < 53 ? 1 : 2)) * 3
                   + (gqw < 49 ? 0 : (gqw < 53 ? 1 : 2));
            float v[4];
            #pragma unroll
            for (int tn = 0; tn < 4; ++tn) {
                float s = sacc[tm][tn][i] * scale;
                s += sBias[wave][(qh - khA[tn] + 6) * 13 + (qw - kwA[tn] + 6)];
                if (rq != rkA[tn]) s -= 100.0f;
                v[tn] = nOK[tn] ? s : -1e30f;
            }
            float mx = fmaxf(fmaxf(v[0], v[1]), fmaxf(v[2], v[3]));
            mx = fmaxf(mx, __shfl_xor(mx, 1));
            mx = fmaxf(mx, __shfl_xor(mx, 2));
            mx = fmaxf(mx, __shfl_xor(mx, 4));
            mx = fmaxf(mx, __shfl_xor(mx, 8));
            float p0 = __expf(v[0] - mx), p1 = __expf(v[1] - mx);
            float p2 = __expf(v[2] - mx), p3 = __expf(v[3] - mx);
            float sum = p0 + p1 + p2 + p3;
            sum += __shfl_xor(sum, 1);
            sum += __shfl_xor(sum, 2);
            sum += __shfl_xor(sum, 4);
            sum += __shfl_xor(sum, 8);
            float inv = 1.0f / sum;
            float pp[4] = { p0 * inv, p1 * inv, p2 * inv, p3 * inv };
            // pack (n, n+1) bf16 pairs via neighbor shfl; even-mrow lanes write
            #pragma unroll
            for (int tn = 0; tn < 4; ++tn) {
                float po = __shfl_xor(pp[tn], 1);
                if (!(mrow & 1)) {
                    unsigned int pk = (unsigned int)f2bf(pp[tn])
                                    | ((unsigned int)f2bf(po) << 16);
                    *(unsigned int*)&sP[wave][m][tn * 16 + mrow] = pk;
                }
            }
        }
    }
    __syncthreads();   // sP ready

    // O^T[d][m] = sum_n V[n][d] * P[m][n] ; A = V^T frags, B = P frags
    f32x4 oacc[2][4] = {};
    #pragma unroll
    for (int ks = 0; ks < 2; ++ks) {
        s16x8 vf[2], pf[4];
        #pragma unroll
        for (int td = 0; td < 2; ++td)
            vf[td] = *(const s16x8*)&sVt[wave][td * 16 + mrow][ks * 32 + quad * 8];
        #pragma unroll
        for (int tm = 0; tm < 4; ++tm)
            pf[tm] = *(const s16x8*)&sP[wave][tm * 16 + mrow][ks * 32 + quad * 8];
        #pragma unroll
        for (int td = 0; td < 2; ++td)
            #pragma unroll
            for (int tm = 0; tm < 4; ++tm)
                oacc[td][tm] = __builtin_amdgcn_mfma_f32_16x16x32_bf16(
                    vf[td], pf[tm], oacc[td][tm], 0, 0, 0);
    }

    // store: lane holds O^T[d = td*16+quad*4+i][m = tm*16+mrow]
    #pragma unroll
    for (int tm = 0; tm < 4; ++tm) {
        int m = tm * 16 + mrow;
        if (m < NWIN) {
            u16* orow = out + ((size_t)(w * NWIN + m)) * C_DIM + h * DHEAD;
            #pragma unroll
            for (int td = 0; td < 2; ++td) {
                u16x4 ov;
                #pragma unroll
                for (int i = 0; i < 4; ++i) ov[i] = f2bf(oacc[td][tm][i]);
                *(u16x4*)(orow + td * 16 + quad * 4) = ov;
            }
        }
    }
}

// ---------------------------------------------------------------------------
// fp32 I/O, bf16 compute core. x2 lives in d_out.
// Workspace: two aliased slots (lifetimes disjoint):
//   slotS = winC -> aoC -> h2C   (CB * 3136 * 512  * 2B per batch)
//   slotL = qkvC -> ffiC         (CB * 3136 * 2048 * 2B per batch)
// CB tiers: 4 (70.7 MB, proven) / 8 (134.9 MB) / 16 (263.4 MB, single chunk).
// ---------------------------------------------------------------------------
extern "C" void kernel_launch(void* const* d_in, const int* in_sizes, int n_in,
                              void* d_out, int out_size, void* d_ws, size_t ws_size,
                              hipStream_t stream)
{
    const float* x       = (const float*)d_in[0];
    const float* emb     = (const float*)d_in[1];
    const float* adaLN_w = (const float*)d_in[2];
    const float* adaLN_b = (const float*)d_in[3];
    const float* qkv_w   = (const float*)d_in[4];
    const float* qkv_b   = (const float*)d_in[5];
    const float* proj_w  = (const float*)d_in[6];
    const float* proj_b  = (const float*)d_in[7];
    const float* relb    = (const float*)d_in[8];
    const float* ff_w1   = (const float*)d_in[9];
    const float* ff_b1   = (const float*)d_in[10];
    const float* ff_w2   = (const float*)d_in[11];
    const float* ff_b2   = (const float*)d_in[12];
    float* outp = (float*)d_out;

    char* ws = (char*)d_ws;
    float* mod   = (float*)(ws + 0);                  //    196,608 B
    u16* wT_qkv  = (u16*)(ws + 196608);               //  1,572,864 B
    u16* wT_proj = (u16*)(ws + 1769472);              //    524,288 B
    u16* wT_ff1  = (u16*)(ws + 2293760);              //  2,097,152 B
    u16* wT_ff2  = (u16*)(ws + 4390912);              //  2,097,152 B
    char* slots  = ws + 6488064;

    const size_t perB_S = (size_t)L_TOK * C_DIM * sizeof(u16);   //  3,211,264
    const size_t perB_L = (size_t)L_TOK * MLP_DIM * sizeof(u16); // 12,845,056

    int CB = 4;   // 70,713,344 B total (proven fit)
    if (ws_size >= 6488064 + 8  * (perB_S + perB_L)) CB = 8;
    if (ws_size >= 6488064 + 16 * (perB_S + perB_L)) CB = 16;

    const int nChunks   = B_SZ / CB;
    const int chunkRows = CB * L_TOK;
    const int nrb       = chunkRows / 256;            // 256-row blocks per chunk
    u16* slotS = (u16*)slots;                         // winC / aoC / h2C
    u16* slotL = (u16*)(slots + (size_t)CB * perB_S); // qkvC / ffiC

    // prolog (once)
    mod_kernel<<<dim3(12, 16), dim3(256), 0, stream>>>(emb, adaLN_w, adaLN_b, mod);
    transpose_kernel<<<dim3(16, 48), dim3(32, 32), 0, stream>>>(qkv_w,  wT_qkv, 512, 1536);
    transpose_kernel<<<dim3(16, 16), dim3(32, 32), 0, stream>>>(proj_w, wT_proj, 512, 512);
    transpose_kernel<<<dim3(16, 64), dim3(32, 32), 0, stream>>>(ff_w1,  wT_ff1, 512, 2048);
    transpose_kernel<<<dim3(64, 16), dim3(32, 32), 0, stream>>>(ff_w2,  wT_ff2, 2048, 512);

    for (int c = 0; c < nChunks; ++c) {
        int row0 = c * chunkRows;
        // LN1 + modulate + shift + window partition: x[row0..] -> slotS (winC)
        ln_kernel<1><<<dim3(chunkRows / 4), dim3(256), 0, stream>>>(
            x, mod, slotS, 0, 512, row0);
        // qkv GEMM: winC @ wT_qkv -> slotL (qkvC)   N=1536 -> 6 col-blocks
        gemm256<0><<<dim3(nrb * 6), dim3(512), 0, stream>>>(
            slotS, wT_qkv, qkv_b, slotL, nullptr, mod, 1536, 512, 0, 6);
        // attention (MFMA): qkvC -> slotS (aoC; winC is dead)
        attn_mfma<<<dim3(CB * 64, 4), dim3(256), 0, stream>>>(slotL, relb, slotS);
        // proj + window reverse + unshift + residual(x) -> d_out (x2, fp32)
        gemm256<2><<<dim3(nrb * 2), dim3(512), 0, stream>>>(
            slotS, wT_proj, proj_b, outp, x, mod, 512, 512, row0, 2);
        // LN2 + modulate: d_out[row0..] -> slotS (h2C; aoC is dead)
        ln_kernel<0><<<dim3(chunkRows / 4), dim3(256), 0, stream>>>(
            outp, mod, slotS, 1536, 2048, row0);
        // FF1 + GELU: h2C -> slotL (ffiC; qkvC is dead)   N=2048 -> 8
        gemm256<1><<<dim3(nrb * 8), dim3(512), 0, stream>>>(
            slotS, wT_ff1, ff_b1, slotL, nullptr, mod, 2048, 512, 0, 8);
        // FF2 + residual(x2) -> d_out   N=512 -> 2
        gemm256<3><<<dim3(nrb * 2), dim3(512), 0, stream>>>(
            slotL, wT_ff2, ff_b2, outp, outp, mod, 512, 2048, row0, 2);
    }
}

// Round 9
// 959.817 us; speedup vs baseline: 1.1583x; 1.0266x over previous
//
#include <hip/hip_runtime.h>
#include <cmath>

typedef unsigned short u16;
typedef unsigned short u16x2 __attribute__((ext_vector_type(2)));
typedef unsigned short u16x4 __attribute__((ext_vector_type(4)));
typedef unsigned short u16x8 __attribute__((ext_vector_type(8)));
typedef short s16x8 __attribute__((ext_vector_type(8)));
typedef float f32x4 __attribute__((ext_vector_type(4)));
typedef float f32x2 __attribute__((ext_vector_type(2)));

#define B_SZ 16
#define HW 56
#define L_TOK 3136      // 56*56
#define C_DIM 512
#define NHEAD 16
#define DHEAD 32
#define WS7 7
#define NWIN 49
#define ROWS_TOTAL 50176   // 16*3136
#define MLP_DIM 2048

__device__ __forceinline__ float bf2f(u16 u) {
    union { unsigned int i; float f; } z;
    z.i = ((unsigned int)u) << 16;
    return z.f;
}
__device__ __forceinline__ u16 f2bf(float f) {
    union { float f; unsigned int i; } z;
    z.f = f;
    unsigned int r = z.i + 0x7fffu + ((z.i >> 16) & 1u);
    return (u16)(r >> 16);
}

// async global->LDS, 16B per lane; LDS dest = wave-uniform base + lane*16
__device__ __forceinline__ void gl_lds16(const u16* g, u16* l) {
    __builtin_amdgcn_global_load_lds(
        (const __attribute__((address_space(1))) unsigned int*)g,
        (__attribute__((address_space(3))) unsigned int*)l,
        16, 0, 0);
}

// ---------------------------------------------------------------------------
// 1) mod = silu(emb) @ adaLN_w + adaLN_b -> fp32 [16,3072]
// ---------------------------------------------------------------------------
__global__ __launch_bounds__(256)
void mod_kernel(const float* __restrict__ emb, const float* __restrict__ w,
                const float* __restrict__ bias, float* __restrict__ mod)
{
    int b = blockIdx.y;
    int o = blockIdx.x * 256 + threadIdx.x;
    __shared__ float se[512];
    for (int i = threadIdx.x; i < 512; i += 256) {
        float e = emb[b * 512 + i];
        se[i] = e / (1.0f + expf(-e));
    }
    __syncthreads();
    float acc = bias[o];
    #pragma unroll 8
    for (int k = 0; k < 512; ++k)
        acc += se[k] * w[(size_t)k * 3072 + o];
    mod[b * 3072 + o] = acc;
}

// ---------------------------------------------------------------------------
// 2) weight transpose + bf16 cast: Wt[n][k] = bf16(W[k][n])
// ---------------------------------------------------------------------------
__global__ __launch_bounds__(1024)
void transpose_kernel(const float* __restrict__ W, u16* __restrict__ Wt, int K, int N)
{
    __shared__ float tile[32][33];
    int k0 = blockIdx.x * 32, n0 = blockIdx.y * 32;
    tile[threadIdx.y][threadIdx.x] = W[(size_t)(k0 + threadIdx.y) * N + (n0 + threadIdx.x)];
    __syncthreads();
    Wt[(size_t)(n0 + threadIdx.y) * K + (k0 + threadIdx.x)] = f2bf(tile[threadIdx.x][threadIdx.y]);
}

// ---------------------------------------------------------------------------
// 3) LN + adaLN modulate; wave-per-row (4 rows/block), no LDS / syncthreads.
// ---------------------------------------------------------------------------
template<int WINDOWED>
__global__ __launch_bounds__(256)
void ln_kernel(const float* __restrict__ xin, const float* __restrict__ mod,
               u16* __restrict__ out, int shOff, int scOff, int rowBase)
{
    int wv   = threadIdx.x >> 6;
    int lane = threadIdx.x & 63;
    int rbl = blockIdx.x * 4 + wv;        // chunk-local row
    int rb  = rbl + rowBase;              // global sequence row
    int b = rb / L_TOK, l = rb - b * L_TOK;
    const float* xr = xin + (size_t)rb * C_DIM;
    int c0 = lane * 8;
    f32x4 u0 = *(const f32x4*)(xr + c0);
    f32x4 u1 = *(const f32x4*)(xr + c0 + 4);
    float s = u0.x + u0.y + u0.z + u0.w + u1.x + u1.y + u1.z + u1.w;
    float q = u0.x*u0.x + u0.y*u0.y + u0.z*u0.z + u0.w*u0.w
            + u1.x*u1.x + u1.y*u1.y + u1.z*u1.z + u1.w*u1.w;
    #pragma unroll
    for (int off = 32; off > 0; off >>= 1) {
        s += __shfl_xor(s, off);
        q += __shfl_xor(q, off);
    }
    float mu = s * (1.0f / 512.0f);
    float var = q * (1.0f / 512.0f) - mu * mu;
    float rstd = rsqrtf(var + 1e-6f);
    const float* mb = mod + b * 3072;
    f32x4 sc0 = *(const f32x4*)(mb + scOff + c0);
    f32x4 sc1 = *(const f32x4*)(mb + scOff + c0 + 4);
    f32x4 sh0 = *(const f32x4*)(mb + shOff + c0);
    f32x4 sh1 = *(const f32x4*)(mb + shOff + c0 + 4);
    float y[8];
    y[0] = (u0.x - mu) * rstd * (1.0f + sc0.x) + sh0.x;
    y[1] = (u0.y - mu) * rstd * (1.0f + sc0.y) + sh0.y;
    y[2] = (u0.z - mu) * rstd * (1.0f + sc0.z) + sh0.z;
    y[3] = (u0.w - mu) * rstd * (1.0f + sc0.w) + sh0.w;
    y[4] = (u1.x - mu) * rstd * (1.0f + sc1.x) + sh1.x;
    y[5] = (u1.y - mu) * rstd * (1.0f + sc1.y) + sh1.y;
    y[6] = (u1.z - mu) * rstd * (1.0f + sc1.z) + sh1.z;
    y[7] = (u1.w - mu) * rstd * (1.0f + sc1.w) + sh1.w;
    size_t drow;
    if (WINDOWED) {
        int hh = l / HW, ww = l - hh * HW;
        int hs = hh - 3; if (hs < 0) hs += HW;
        int ws2 = ww - 3; if (ws2 < 0) ws2 += HW;
        int wi = (hs / WS7) * 8 + (ws2 / WS7);
        int n  = (hs % WS7) * WS7 + (ws2 % WS7);
        int b_local = rbl / L_TOK;
        drow = (size_t)((b_local * 64 + wi) * NWIN + n);
    } else {
        drow = (size_t)rbl;
    }
    u16x8 o;
    #pragma unroll
    for (int i = 0; i < 8; ++i) o[i] = f2bf(y[i]);
    *(u16x8*)(out + drow * C_DIM + c0) = o;
}

// ---------------------------------------------------------------------------
// 4) GEMM: C[M,N] = A[M,K] @ Bt[N,K]^T + bias
//    m201-style 8-phase 256x256 tile, BK=64, 8 waves (2M x 4N), per-wave
//    128x64 output, acc[8][4].  (Schedule unchanged from r8 — verified.)
//    r9: epilogue de-VALU'd.  r8 PMC: VALUBusy 38% >> MfmaUtil 19.6% —
//    the per-element epilogue (erff, per-element row-decode, 128 bias/mod
//    loads) was ~2x the matrix-pipe work.  Now: bias/col hoisted to 4 regs,
//    row-decode once per row (32/lane), GELU via tanh-form (1 __expf,
//    |err| ~1e-3 << 0.111 threshold).
// ---------------------------------------------------------------------------
template<int EPI>
__global__ __launch_bounds__(512)
void gemm256(const u16* __restrict__ A, const u16* __restrict__ Bt,
             const float* __restrict__ bias, void* __restrict__ outv,
             const float* __restrict__ resid, const float* __restrict__ mod,
             int N, int K, int rowOffset, int nyb)
{
    __shared__ u16 sA[2][2][256][32];   // [buf][kh][row][chunk*8] = 64 KB
    __shared__ u16 sB[2][2][256][32];   // 64 KB
    const int tid  = threadIdx.x;
    const int lane = tid & 63;
    const int wave = tid >> 6;       // 0..7
    const int wm = wave >> 2;        // 0..1 : 128-row half
    const int wn = wave & 3;         // 0..3 : 64-col quarter
    const int quad = lane >> 4;
    const int mrow = lane & 15;

    // bijective XCD-chunked swizzle (m204), col-block fastest within chunk
    const int nwg  = gridDim.x;
    const int orig = blockIdx.x;
    const int xq = nwg >> 3, xr = nwg & 7;
    const int xcd = orig & 7, xidx = orig >> 3;
    const int wgid = (xcd < xr ? xcd * (xq + 1)
                               : xr * (xq + 1) + (xcd - xr) * xq) + xidx;
    const int bx = wgid / nyb;
    const int by = wgid - bx * nyb;
    const int rowBase = bx * 256;
    const int colBase = by * 256;

    // staging: wave stages rows [wave*32, wave*32+32) of the 256-row panel,
    // 2 gl_lds per half-tile (16 rows each).  Pre-swizzled global source.
    const int laneRow = lane >> 2;
    const int swz = ((lane & 3) ^ ((lane >> 3) & 3)) * 8;   // u16 offset
    const u16* pA0 = A  + (size_t)(rowBase + wave * 32 + laneRow) * K + swz;
    const u16* pA1 = pA0 + (size_t)16 * K;
    const u16* pB0 = Bt + (size_t)(colBase + wave * 32 + laneRow) * K + swz;
    const u16* pB1 = pB0 + (size_t)16 * K;
    // read-side physical chunk (u16 offset) for logical k-chunk 'quad'
    const int cq8 = (quad ^ ((mrow >> 1) & 3)) * 8;

    f32x4 acc[8][4] = {};
    s16x8 af[4], bg[4];
    const int NKT  = K >> 6;          // K-tiles of 64
    const int nkt4 = NKT << 2;        // total half-tile entries

#define STAGE_E(idx) do {                                            \
    const int _kt = (idx) >> 2, _e = (idx) & 3;                      \
    const int _buf = _kt & 1, _kh = _e >> 1;                         \
    const int _ko = _kt * 64 + _kh * 32;                             \
    if (_e & 1) {                                                    \
        gl_lds16(pB0 + _ko, &sB[_buf][_kh][wave * 32][0]);           \
        gl_lds16(pB1 + _ko, &sB[_buf][_kh][wave * 32 + 16][0]);      \
    } else {                                                         \
        gl_lds16(pA0 + _ko, &sA[_buf][_kh][wave * 32][0]);           \
        gl_lds16(pA1 + _ko, &sA[_buf][_kh][wave * 32 + 16][0]);      \
    }                                                                \
} while (0)

#define PHASE(_mh, _ks, _rdB) do {                                           \
    _Pragma("unroll")                                                        \
    for (int mi = 0; mi < 4; ++mi)                                           \
        af[mi] = *(const s16x8*)                                             \
            &sA[buf][_ks][wm * 128 + ((_mh) * 4 + mi) * 16 + mrow][cq8];     \
    if (_rdB) {                                                              \
        _Pragma("unroll")                                                    \
        for (int nf = 0; nf < 4; ++nf)                                       \
            bg[nf] = *(const s16x8*)                                         \
                &sB[buf][_ks][wn * 64 + nf * 16 + mrow][cq8];                \
    }                                                                        \
    if (sidx < nkt4) STAGE_E(sidx);                                          \
    ++sidx;                                                                  \
    __builtin_amdgcn_s_barrier();                                            \
    asm volatile("s_waitcnt lgkmcnt(0)" ::: "memory");                       \
    __builtin_amdgcn_sched_barrier(0);                                       \
    __builtin_amdgcn_s_setprio(1);                                           \
    _Pragma("unroll")                                                        \
    for (int mi = 0; mi < 4; ++mi)                                           \
        _Pragma("unroll")                                                    \
        for (int nf = 0; nf < 4; ++nf)                                       \
            acc[(_mh) * 4 + mi][nf] = __builtin_amdgcn_mfma_f32_16x16x32_bf16( \
                af[mi], bg[nf], acc[(_mh) * 4 + mi][nf], 0, 0, 0);           \
    __builtin_amdgcn_s_setprio(0);                                           \
    __builtin_amdgcn_s_barrier();                                            \
    __builtin_amdgcn_sched_barrier(0);                                       \
} while (0)

    int sidx = 6;
    // prologue: stage S[0..5] = kt0 fully + kt1 {A-kh0, B-kh0}
    STAGE_E(0); STAGE_E(1); STAGE_E(2); STAGE_E(3); STAGE_E(4); STAGE_E(5);

    for (int kt = 0; kt < NKT; ++kt) {
        const int buf = kt & 1;
        if (kt == NKT - 1)
            asm volatile("s_waitcnt vmcnt(0)" ::: "memory");
        else
            asm volatile("s_waitcnt vmcnt(4)" ::: "memory");
        __builtin_amdgcn_s_barrier();
        __builtin_amdgcn_sched_barrier(0);
        PHASE(0, 0, true);
        PHASE(1, 0, false);
        PHASE(0, 1, true);
        PHASE(1, 1, false);
    }
#undef STAGE_E
#undef PHASE

    // ---- epilogue (r9: de-VALU'd) ----
    // per-col constants: independent of row -> 4 loads total
    int colx[4];
    float bv[4];
    #pragma unroll
    for (int nf = 0; nf < 4; ++nf) {
        colx[nf] = colBase + wn * 64 + nf * 16 + mrow;
        bv[nf] = bias[colx[nf]];
    }

    #pragma unroll
    for (int mf = 0; mf < 8; ++mf) {
        #pragma unroll
        for (int i = 0; i < 4; ++i) {
            const int r = rowBase + wm * 128 + mf * 16 + quad * 4 + i; // chunk-local
            if constexpr (EPI == 0) {
                u16* orow = (u16*)outv + (size_t)r * N;
                #pragma unroll
                for (int nf = 0; nf < 4; ++nf)
                    orow[colx[nf]] = f2bf(acc[mf][nf][i] + bv[nf]);
            } else if constexpr (EPI == 1) {
                u16* orow = (u16*)outv + (size_t)r * N;
                #pragma unroll
                for (int nf = 0; nf < 4; ++nf) {
                    float v = acc[mf][nf][i] + bv[nf];
                    // tanh-form GELU: 0.5v(1+tanh(0.79788456(v+0.044715v^3)))
                    //               = v * sigmoid(1.59576912*v*(1+0.044715v^2))
                    float a = 1.5957691216057308f * v * (1.0f + 0.044715f * v * v);
                    float g = v / (1.0f + __expf(-a));
                    orow[colx[nf]] = f2bf(g);
                }
            } else if constexpr (EPI == 2) {
                // row-decode once per row (was per element)
                int rg = r + rowOffset;        // global window-layout row
                int b = rg / L_TOK;
                int rem = rg - b * L_TOK;
                int wi = rem / NWIN;
                int n  = rem - wi * NWIN;
                int hs  = (wi >> 3) * WS7 + n / WS7;
                int ws2 = (wi & 7) * WS7 + n % WS7;
                int hh = hs + 3;  if (hh >= HW)  hh -= HW;
                int ww = ws2 + 3; if (ww >= HW)  ww -= HW;
                size_t rbase = ((size_t)(b * L_TOK + hh * HW + ww)) * C_DIM;
                float* orow       = (float*)outv + rbase;
                const float* rrow = resid + rbase;
                const float* grow = mod + b * 3072 + 1024;
                #pragma unroll
                for (int nf = 0; nf < 4; ++nf) {
                    int c = colx[nf];
                    orow[c] = rrow[c] + grow[c] * (acc[mf][nf][i] + bv[nf]);
                }
            } else {  // EPI == 3
                int rg = r + rowOffset;        // global sequence row
                int b = rg / L_TOK;
                size_t rbase = (size_t)rg * C_DIM;
                float* orow       = (float*)outv + rbase;
                const float* rrow = resid + rbase;
                const float* grow = mod + b * 3072 + 2560;
                #pragma unroll
                for (int nf = 0; nf < 4; ++nf) {
                    int c = colx[nf];
                    orow[c] = rrow[c] + grow[c] * (acc[mf][nf][i] + bv[nf]);
                }
            }
        }
    }
}

// ---------------------------------------------------------------------------
// 5) MFMA windowed attention. Block = 4 waves = 4 heads of one window.
// ---------------------------------------------------------------------------
__global__ __launch_bounds__(256)
void attn_mfma(const u16* __restrict__ qkv, const float* __restrict__ bias_table,
               u16* __restrict__ out)
{
    const int w    = blockIdx.x;          // chunk-local: b_local*64 + wi
    const int hg   = blockIdx.y;          // 0..3
    const int wave = threadIdx.x >> 6;
    const int lane = threadIdx.x & 63;
    const int h    = hg * 4 + wave;
    const int wi   = w & 63;
    const int quad = lane >> 4;
    const int mrow = lane & 15;

    __shared__ u16 sP[4][64][72];      // per-wave P (bf16), pitch 72 (144B rows)
    __shared__ u16 sVt[4][32][72];     // per-wave V^T (bf16)
    __shared__ float sBias[4][169];    // per-wave head bias slice

    const u16* qb = qkv + (size_t)w * NWIN * 1536 + h * DHEAD;

    // stage per-head bias slice (strided global, L2-resident table)
    for (int e = lane; e < 169; e += 64)
        sBias[wave][e] = bias_table[e * NHEAD + h];

    // stage V transposed: rows 0..48 real, 49..63 zeroed
    #pragma unroll
    for (int rr = 0; rr < 4; ++rr) {
        int e = rr * 64 + lane;
        int r = e >> 2, d0 = (e & 3) * 8;
        u16x8 vv = {};
        if (e < 196)
            vv = *(const u16x8*)(qb + (size_t)r * 1536 + 1024 + d0);
        #pragma unroll
        for (int j = 0; j < 8; ++j)
            sVt[wave][d0 + j][r] = vv[j];
    }

    // Q/K fragments direct from global; pad rows (49..63) clamped to 48
    s16x8 qf[4], kf[4];
    #pragma unroll
    for (int t = 0; t < 4; ++t) {
        int r = t * 16 + mrow; if (r > 48) r = 48;
        qf[t] = *(const s16x8*)(qb + (size_t)r * 1536 + quad * 8);
        kf[t] = *(const s16x8*)(qb + (size_t)r * 1536 + 512 + quad * 8);
    }
    __syncthreads();   // sVt / sBias visible

    // S = Q K^T : S[m][n], m = tm*16+quad*4+i, n = tn*16+mrow
    f32x4 sacc[4][4] = {};
    #pragma unroll
    for (int tm = 0; tm < 4; ++tm)
        #pragma unroll
        for (int tn = 0; tn < 4; ++tn)
            sacc[tm][tn] = __builtin_amdgcn_mfma_f32_16x16x32_bf16(
                qf[tm], kf[tn], sacc[tm][tn], 0, 0, 0);

    const float scale = 0.17677669529663687f;   // 1/sqrt(32)
    const int wh = wi >> 3, ww = wi & 7;

    // per-lane key-side terms (constant across tm,i)
    int khA[4], kwA[4], rkA[4], nOK[4];
    #pragma unroll
    for (int tn = 0; tn < 4; ++tn) {
        int n = tn * 16 + mrow;
        nOK[tn] = (n < NWIN);
        int nc = n > 48 ? 48 : n;
        khA[tn] = nc / 7; kwA[tn] = nc - khA[tn] * 7;
        int gkh = wh * 7 + khA[tn], gkw = ww * 7 + kwA[tn];
        rkA[tn] = (gkh < 49 ? 0 : (gkh < 53 ? 1 : 2)) * 3
                + (gkw < 49 ? 0 : (gkw < 53 ? 1 : 2));
    }

    #pragma unroll
    for (int tm = 0; tm < 4; ++tm) {
        #pragma unroll
        for (int i = 0; i < 4; ++i) {
            int m = tm * 16 + quad * 4 + i;
            int mc = m > 48 ? 48 : m;            // garbage rows: keep idx bounded
            int qh = mc / 7, qw = mc - qh * 7;
            int gqh = wh * 7 + qh, gqw = ww * 7 + qw;
            int rq = (gqh < 49 ? 0 : (gqh < 53 ? 1 : 2)) * 3
                   + (gqw < 49 ? 0 : (gqw < 53 ? 1 : 2));
            float v[4];
            #pragma unroll
            for (int tn = 0; tn < 4; ++tn) {
                float s = sacc[tm][tn][i] * scale;
                s += sBias[wave][(qh - khA[tn] + 6) * 13 + (qw - kwA[tn] + 6)];
                if (rq != rkA[tn]) s -= 100.0f;
                v[tn] = nOK[tn] ? s : -1e30f;
            }
            float mx = fmaxf(fmaxf(v[0], v[1]), fmaxf(v[2], v[3]));
            mx = fmaxf(mx, __shfl_xor(mx, 1));
            mx = fmaxf(mx, __shfl_xor(mx, 2));
            mx = fmaxf(mx, __shfl_xor(mx, 4));
            mx = fmaxf(mx, __shfl_xor(mx, 8));
            float p0 = __expf(v[0] - mx), p1 = __expf(v[1] - mx);
            float p2 = __expf(v[2] - mx), p3 = __expf(v[3] - mx);
            float sum = p0 + p1 + p2 + p3;
            sum += __shfl_xor(sum, 1);
            sum += __shfl_xor(sum, 2);
            sum += __shfl_xor(sum, 4);
            sum += __shfl_xor(sum, 8);
            float inv = 1.0f / sum;
            float pp[4] = { p0 * inv, p1 * inv, p2 * inv, p3 * inv };
            // pack (n, n+1) bf16 pairs via neighbor shfl; even-mrow lanes write
            #pragma unroll
            for (int tn = 0; tn < 4; ++tn) {
                float po = __shfl_xor(pp[tn], 1);
                if (!(mrow & 1)) {
                    unsigned int pk = (unsigned int)f2bf(pp[tn])
                                    | ((unsigned int)f2bf(po) << 16);
                    *(unsigned int*)&sP[wave][m][tn * 16 + mrow] = pk;
                }
            }
        }
    }
    __syncthreads();   // sP ready

    // O^T[d][m] = sum_n V[n][d] * P[m][n] ; A = V^T frags, B = P frags
    f32x4 oacc[2][4] = {};
    #pragma unroll
    for (int ks = 0; ks < 2; ++ks) {
        s16x8 vf[2], pf[4];
        #pragma unroll
        for (int td = 0; td < 2; ++td)
            vf[td] = *(const s16x8*)&sVt[wave][td * 16 + mrow][ks * 32 + quad * 8];
        #pragma unroll
        for (int tm = 0; tm < 4; ++tm)
            pf[tm] = *(const s16x8*)&sP[wave][tm * 16 + mrow][ks * 32 + quad * 8];
        #pragma unroll
        for (int td = 0; td < 2; ++td)
            #pragma unroll
            for (int tm = 0; tm < 4; ++tm)
                oacc[td][tm] = __builtin_amdgcn_mfma_f32_16x16x32_bf16(
                    vf[td], pf[tm], oacc[td][tm], 0, 0, 0);
    }

    // store: lane holds O^T[d = td*16+quad*4+i][m = tm*16+mrow]
    #pragma unroll
    for (int tm = 0; tm < 4; ++tm) {
        int m = tm * 16 + mrow;
        if (m < NWIN) {
            u16* orow = out + ((size_t)(w * NWIN + m)) * C_DIM + h * DHEAD;
            #pragma unroll
            for (int td = 0; td < 2; ++td) {
                u16x4 ov;
                #pragma unroll
                for (int i = 0; i < 4; ++i) ov[i] = f2bf(oacc[td][tm][i]);
                *(u16x4*)(orow + td * 16 + quad * 4) = ov;
            }
        }
    }
}

// ---------------------------------------------------------------------------
// fp32 I/O, bf16 compute core. x2 lives in d_out.
// Workspace: two aliased slots (lifetimes disjoint):
//   slotS = winC -> aoC -> h2C   (CB * 3136 * 512  * 2B per batch)
//   slotL = qkvC -> ffiC         (CB * 3136 * 2048 * 2B per batch)
// CB tiers: 4 (70.7 MB, proven) / 8 (134.9 MB) / 16 (263.4 MB, single chunk).
// ---------------------------------------------------------------------------
extern "C" void kernel_launch(void* const* d_in, const int* in_sizes, int n_in,
                              void* d_out, int out_size, void* d_ws, size_t ws_size,
                              hipStream_t stream)
{
    const float* x       = (const float*)d_in[0];
    const float* emb     = (const float*)d_in[1];
    const float* adaLN_w = (const float*)d_in[2];
    const float* adaLN_b = (const float*)d_in[3];
    const float* qkv_w   = (const float*)d_in[4];
    const float* qkv_b   = (const float*)d_in[5];
    const float* proj_w  = (const float*)d_in[6];
    const float* proj_b  = (const float*)d_in[7];
    const float* relb    = (const float*)d_in[8];
    const float* ff_w1   = (const float*)d_in[9];
    const float* ff_b1   = (const float*)d_in[10];
    const float* ff_w2   = (const float*)d_in[11];
    const float* ff_b2   = (const float*)d_in[12];
    float* outp = (float*)d_out;

    char* ws = (char*)d_ws;
    float* mod   = (float*)(ws + 0);                  //    196,608 B
    u16* wT_qkv  = (u16*)(ws + 196608);               //  1,572,864 B
    u16* wT_proj = (u16*)(ws + 1769472);              //    524,288 B
    u16* wT_ff1  = (u16*)(ws + 2293760);              //  2,097,152 B
    u16* wT_ff2  = (u16*)(ws + 4390912);              //  2,097,152 B
    char* slots  = ws + 6488064;

    const size_t perB_S = (size_t)L_TOK * C_DIM * sizeof(u16);   //  3,211,264
    const size_t perB_L = (size_t)L_TOK * MLP_DIM * sizeof(u16); // 12,845,056

    int CB = 4;   // 70,713,344 B total (proven fit)
    if (ws_size >= 6488064 + 8  * (perB_S + perB_L)) CB = 8;
    if (ws_size >= 6488064 + 16 * (perB_S + perB_L)) CB = 16;

    const int nChunks   = B_SZ / CB;
    const int chunkRows = CB * L_TOK;
    const int nrb       = chunkRows / 256;            // 256-row blocks per chunk
    u16* slotS = (u16*)slots;                         // winC / aoC / h2C
    u16* slotL = (u16*)(slots + (size_t)CB * perB_S); // qkvC / ffiC

    // prolog (once)
    mod_kernel<<<dim3(12, 16), dim3(256), 0, stream>>>(emb, adaLN_w, adaLN_b, mod);
    transpose_kernel<<<dim3(16, 48), dim3(32, 32), 0, stream>>>(qkv_w,  wT_qkv, 512, 1536);
    transpose_kernel<<<dim3(16, 16), dim3(32, 32), 0, stream>>>(proj_w, wT_proj, 512, 512);
    transpose_kernel<<<dim3(16, 64), dim3(32, 32), 0, stream>>>(ff_w1,  wT_ff1, 512, 2048);
    transpose_kernel<<<dim3(64, 16), dim3(32, 32), 0, stream>>>(ff_w2,  wT_ff2, 2048, 512);

    for (int c = 0; c < nChunks; ++c) {
        int row0 = c * chunkRows;
        // LN1 + modulate + shift + window partition: x[row0..] -> slotS (winC)
        ln_kernel<1><<<dim3(chunkRows / 4), dim3(256), 0, stream>>>(
            x, mod, slotS, 0, 512, row0);
        // qkv GEMM: winC @ wT_qkv -> slotL (qkvC)   N=1536 -> 6 col-blocks
        gemm256<0><<<dim3(nrb * 6), dim3(512), 0, stream>>>(
            slotS, wT_qkv, qkv_b, slotL, nullptr, mod, 1536, 512, 0, 6);
        // attention (MFMA): qkvC -> slotS (aoC; winC is dead)
        attn_mfma<<<dim3(CB * 64, 4), dim3(256), 0, stream>>>(slotL, relb, slotS);
        // proj + window reverse + unshift + residual(x) -> d_out (x2, fp32)
        gemm256<2><<<dim3(nrb * 2), dim3(512), 0, stream>>>(
            slotS, wT_proj, proj_b, outp, x, mod, 512, 512, row0, 2);
        // LN2 + modulate: d_out[row0..] -> slotS (h2C; aoC is dead)
        ln_kernel<0><<<dim3(chunkRows / 4), dim3(256), 0, stream>>>(
            outp, mod, slotS, 1536, 2048, row0);
        // FF1 + GELU: h2C -> slotL (ffiC; qkvC is dead)   N=2048 -> 8
        gemm256<1><<<dim3(nrb * 8), dim3(512), 0, stream>>>(
            slotS, wT_ff1, ff_b1, slotL, nullptr, mod, 2048, 512, 0, 8);
        // FF2 + residual(x2) -> d_out   N=512 -> 2
        gemm256<3><<<dim3(nrb * 2), dim3(512), 0, stream>>>(
            slotL, wT_ff2, ff_b2, outp, outp, mod, 512, 2048, row0, 2);
    }
}